// Round 1
// baseline (531.917 us; speedup 1.0000x reference)
//
#include <hip/hip_runtime.h>
#include <hip/hip_bf16.h>
#include <cstddef>

#define B_      2
#define QD_     128
#define NQ_     (QD_ * QD_)          // 16384
#define EMBED_  256
#define HEADS_  8
#define POINTS_ 4
#define D_      32
#define FFN_    512
#define RTOT_   (B_ * NQ_)           // 32768
#define NCAT_   (EMBED_ + HEADS_*POINTS_*2 + HEADS_*POINTS_)  // 256+64+32 = 352

// ---------------------------------------------------------------------------
// concat W_val | W_off | W_attn into Wcat (256 x 352), biases into bcat (352)
// ---------------------------------------------------------------------------
__global__ void concat_w(const float* __restrict__ Wv, const float* __restrict__ Wo,
                         const float* __restrict__ Wa, const float* __restrict__ bv,
                         const float* __restrict__ bo, const float* __restrict__ ba,
                         float* __restrict__ Wcat, float* __restrict__ bcat) {
    int idx = blockIdx.x * 256 + threadIdx.x;
    const int total = EMBED_ * NCAT_;
    if (idx < total) {
        int k = idx / NCAT_;
        int c = idx - k * NCAT_;
        float v;
        if (c < 256)       v = Wv[k * 256 + c];
        else if (c < 320)  v = Wo[k * 64 + (c - 256)];
        else               v = Wa[k * 32 + (c - 320)];
        Wcat[idx] = v;
    }
    if (idx < NCAT_) {
        float v;
        if (idx < 256)      v = bv[idx];
        else if (idx < 320) v = bo[idx - 256];
        else                v = ba[idx - 320];
        bcat[idx] = v;
    }
}

// ---------------------------------------------------------------------------
// Tiled f32 GEMM: C[M,N] = A[M,K] @ B[K,N] + bias[N]  (+ epilogue)
// 64x64 tile, BK=16, 256 threads, 4x4 micro-tile per thread.
// M must be a multiple of 64; N,K multiples of 4 (N guarded).
// ---------------------------------------------------------------------------
enum EpKind { EP_NONE = 0, EP_RELU = 1, EP_ADD2Q = 2 };

template <int EP>
__global__ __launch_bounds__(256) void gemm64(
        const float* __restrict__ A, const float* __restrict__ Bm,
        const float* __restrict__ bias, const float* __restrict__ extra,
        float* __restrict__ C, int M, int N, int K) {
    __shared__ float As[16][68];
    __shared__ float Bs[16][68];

    const int t  = threadIdx.x;
    const int tx = t & 15;
    const int ty = t >> 4;
    const int row0 = blockIdx.y * 64;
    const int col0 = blockIdx.x * 64;

    float acc[4][4] = {};

    for (int k0 = 0; k0 < K; k0 += 16) {
        // stage A tile (64 rows x 16 k), transposed into As[k][row]
        {
            const int r  = t >> 2;
            const int kk = (t & 3) * 4;
            const float4 av = *(const float4*)(A + (size_t)(row0 + r) * K + k0 + kk);
            As[kk + 0][r] = av.x;
            As[kk + 1][r] = av.y;
            As[kk + 2][r] = av.z;
            As[kk + 3][r] = av.w;
        }
        // stage B tile (16 k x 64 cols)
        {
            const int kk = t >> 4;
            const int c  = (t & 15) * 4;
            const int gc = col0 + c;
            float4 bv;
            if (gc + 3 < N) {
                bv = *(const float4*)(Bm + (size_t)(k0 + kk) * N + gc);
            } else {
                bv.x = (gc + 0 < N) ? Bm[(size_t)(k0 + kk) * N + gc + 0] : 0.f;
                bv.y = (gc + 1 < N) ? Bm[(size_t)(k0 + kk) * N + gc + 1] : 0.f;
                bv.z = (gc + 2 < N) ? Bm[(size_t)(k0 + kk) * N + gc + 2] : 0.f;
                bv.w = (gc + 3 < N) ? Bm[(size_t)(k0 + kk) * N + gc + 3] : 0.f;
            }
            *(float4*)&Bs[kk][c] = bv;
        }
        __syncthreads();

        #pragma unroll
        for (int kk = 0; kk < 16; ++kk) {
            const float4 a4 = *(const float4*)&As[kk][ty * 4];
            const float4 b4 = *(const float4*)&Bs[kk][tx * 4];
            acc[0][0] += a4.x * b4.x; acc[0][1] += a4.x * b4.y;
            acc[0][2] += a4.x * b4.z; acc[0][3] += a4.x * b4.w;
            acc[1][0] += a4.y * b4.x; acc[1][1] += a4.y * b4.y;
            acc[1][2] += a4.y * b4.z; acc[1][3] += a4.y * b4.w;
            acc[2][0] += a4.z * b4.x; acc[2][1] += a4.z * b4.y;
            acc[2][2] += a4.z * b4.z; acc[2][3] += a4.z * b4.w;
            acc[3][0] += a4.w * b4.x; acc[3][1] += a4.w * b4.y;
            acc[3][2] += a4.w * b4.z; acc[3][3] += a4.w * b4.w;
        }
        __syncthreads();
    }

    #pragma unroll
    for (int ii = 0; ii < 4; ++ii) {
        const int row = row0 + ty * 4 + ii;
        const int col = col0 + tx * 4;
        if (col + 3 < N) {
            float4 r4;
            r4.x = acc[ii][0] + bias[col + 0];
            r4.y = acc[ii][1] + bias[col + 1];
            r4.z = acc[ii][2] + bias[col + 2];
            r4.w = acc[ii][3] + bias[col + 3];
            if (EP == EP_RELU) {
                r4.x = fmaxf(r4.x, 0.f); r4.y = fmaxf(r4.y, 0.f);
                r4.z = fmaxf(r4.z, 0.f); r4.w = fmaxf(r4.w, 0.f);
            }
            if (EP == EP_ADD2Q) {
                const float4 q4 = *(const float4*)(extra + (size_t)row * N + col);
                r4.x += 2.f * q4.x; r4.y += 2.f * q4.y;
                r4.z += 2.f * q4.z; r4.w += 2.f * q4.w;
            }
            *(float4*)(C + (size_t)row * N + col) = r4;
        } else {
            #pragma unroll
            for (int j = 0; j < 4; ++j) {
                if (col + j < N) {
                    float v = acc[ii][j] + bias[col + j];
                    if (EP == EP_RELU)  v = fmaxf(v, 0.f);
                    if (EP == EP_ADD2Q) v += 2.f * extra[(size_t)row * N + col + j];
                    C[(size_t)row * N + col + j] = v;
                }
            }
        }
    }
}

// ---------------------------------------------------------------------------
// MSDA sampling: per query row r = b*NQ+n, 256 threads = (head h, dim d).
// proj row layout: [0,256) value, [256,320) off (h,p,2), [320,352) attn logits.
// v[b][h][nv][d] = proj[(b*NQ+nv)*352 + h*32 + d]
// ---------------------------------------------------------------------------
__global__ __launch_bounds__(256) void msda_sample(const float* __restrict__ proj,
                                                   float* __restrict__ msda) {
    const int r  = blockIdx.x;          // b*NQ + n
    const int n  = r & (NQ_ - 1);
    const int bq = r >> 14;
    const int gi = n >> 7;              // grid row  (y)
    const int gj = n & 127;             // grid col  (x)
    const int h  = threadIdx.x >> 5;
    const int d  = threadIdx.x & 31;

    const float* prow = proj + (size_t)r * NCAT_;

    // softmax over the 4 points of this head
    float l0 = prow[320 + h * 4 + 0];
    float l1 = prow[320 + h * 4 + 1];
    float l2 = prow[320 + h * 4 + 2];
    float l3 = prow[320 + h * 4 + 3];
    float mx = fmaxf(fmaxf(l0, l1), fmaxf(l2, l3));
    float e0 = expf(l0 - mx), e1 = expf(l1 - mx), e2 = expf(l2 - mx), e3 = expf(l3 - mx);
    const float inv = 1.0f / (e0 + e1 + e2 + e3);
    float aw[4] = {e0 * inv, e1 * inv, e2 * inv, e3 * inv};

    const float* vbase = proj + (size_t)bq * NQ_ * NCAT_ + h * 32 + d;

    float acc = 0.f;
    #pragma unroll
    for (int p = 0; p < 4; ++p) {
        const float ox = prow[256 + h * 8 + p * 2 + 0];
        const float oy = prow[256 + h * 8 + p * 2 + 1];
        // loc = ref + off/128 ; px = loc*128 - 0.5
        const float px = (gj * (1.0f / 127.0f) + ox * (1.0f / 128.0f)) * 128.0f - 0.5f;
        const float py = (gi * (1.0f / 127.0f) + oy * (1.0f / 128.0f)) * 128.0f - 0.5f;
        const float x0f = floorf(px), y0f = floorf(py);
        const int   x0 = (int)x0f, y0 = (int)y0f;
        const float fx = px - x0f, fy = py - y0f;
        const float w00 = (1.f - fx) * (1.f - fy);
        const float w01 = fx * (1.f - fy);
        const float w10 = (1.f - fx) * fy;
        const float w11 = fx * fy;

        float s = 0.f;
        const int x1 = x0 + 1, y1 = y0 + 1;
        if (((unsigned)x0 <= 127u) & ((unsigned)y0 <= 127u))
            s += w00 * vbase[(size_t)(y0 * 128 + x0) * NCAT_];
        if (((unsigned)x1 <= 127u) & ((unsigned)y0 <= 127u))
            s += w01 * vbase[(size_t)(y0 * 128 + x1) * NCAT_];
        if (((unsigned)x0 <= 127u) & ((unsigned)y1 <= 127u))
            s += w10 * vbase[(size_t)(y1 * 128 + x0) * NCAT_];
        if (((unsigned)x1 <= 127u) & ((unsigned)y1 <= 127u))
            s += w11 * vbase[(size_t)(y1 * 128 + x1) * NCAT_];

        acc += aw[p] * s;
    }
    msda[(size_t)r * EMBED_ + h * 32 + d] = acc;
}

// ---------------------------------------------------------------------------
// LayerNorm(y) * gamma + beta + x  -> x (in d_out).  One wave per row.
// ---------------------------------------------------------------------------
__global__ __launch_bounds__(256) void ln_add(const float* __restrict__ y,
                                              const float* __restrict__ gamma,
                                              const float* __restrict__ beta,
                                              float* __restrict__ xout) {
    const int wave = threadIdx.x >> 6;
    const int lane = threadIdx.x & 63;
    const size_t row = (size_t)blockIdx.x * 4 + wave;

    const float4 yv = *(const float4*)(y + row * EMBED_ + lane * 4);
    float s  = yv.x + yv.y + yv.z + yv.w;
    float sq = yv.x * yv.x + yv.y * yv.y + yv.z * yv.z + yv.w * yv.w;
    #pragma unroll
    for (int o = 32; o; o >>= 1) {
        s  += __shfl_xor(s, o, 64);
        sq += __shfl_xor(sq, o, 64);
    }
    const float m   = s * (1.0f / EMBED_);
    const float var = sq * (1.0f / EMBED_) - m * m;
    const float rs  = rsqrtf(var + 1e-5f);

    const float4 xv = *(const float4*)(xout + row * EMBED_ + lane * 4);
    const float4 g  = *(const float4*)(gamma + lane * 4);
    const float4 bt = *(const float4*)(beta + lane * 4);
    float4 o4;
    o4.x = xv.x + (yv.x - m) * rs * g.x + bt.x;
    o4.y = xv.y + (yv.y - m) * rs * g.y + bt.y;
    o4.z = xv.z + (yv.z - m) * rs * g.z + bt.z;
    o4.w = xv.w + (yv.w - m) * rs * g.w + bt.w;
    *(float4*)(xout + row * EMBED_ + lane * 4) = o4;
}

// ---------------------------------------------------------------------------
extern "C" void kernel_launch(void* const* d_in, const int* in_sizes, int n_in,
                              void* d_out, int out_size, void* d_ws, size_t ws_size,
                              hipStream_t stream) {
    const float* q      = (const float*)d_in[0];
    const float* W_off  = (const float*)d_in[1];
    const float* b_off  = (const float*)d_in[2];
    const float* W_attn = (const float*)d_in[3];
    const float* b_attn = (const float*)d_in[4];
    const float* W_val  = (const float*)d_in[5];
    const float* b_val  = (const float*)d_in[6];
    const float* W_out  = (const float*)d_in[7];
    const float* b_out  = (const float*)d_in[8];
    const float* W1     = (const float*)d_in[9];
    const float* b1     = (const float*)d_in[10];
    const float* W2     = (const float*)d_in[11];
    const float* b2     = (const float*)d_in[12];
    const float* gamma  = (const float*)d_in[13];
    const float* beta   = (const float*)d_in[14];

    float* x = (float*)d_out;               // x lives in d_out

    float* ws = (float*)d_ws;
    float* proj   = ws;                                   // RTOT_*NCAT_  = 11,534,336
    float* wcat   = proj + (size_t)RTOT_ * NCAT_;         // 256*352     = 90,112
    float* bcat   = wcat + (size_t)EMBED_ * NCAT_;        // 352
    float* msda   = bcat + NCAT_;                         // RTOT_*256   = 8,388,608
    float* hidden = msda + (size_t)RTOT_ * EMBED_;        // RTOT_*512   = 16,777,216
    float* ybuf   = msda;                                 // reuse msda for y

    concat_w<<<(EMBED_ * NCAT_ + 255) / 256, 256, 0, stream>>>(
        W_val, W_off, W_attn, b_val, b_off, b_attn, wcat, bcat);

    // proj = q @ Wcat + bcat           (32768 x 352 x 256)
    gemm64<EP_NONE><<<dim3((NCAT_ + 63) / 64, RTOT_ / 64), 256, 0, stream>>>(
        q, wcat, bcat, nullptr, proj, RTOT_, NCAT_, EMBED_);

    // MSDA sampling -> msda            (32768 x 256)
    msda_sample<<<RTOT_, 256, 0, stream>>>(proj, msda);

    // x = msda @ W_out + b_out + 2q    (32768 x 256 x 256)
    gemm64<EP_ADD2Q><<<dim3(EMBED_ / 64, RTOT_ / 64), 256, 0, stream>>>(
        msda, W_out, b_out, q, x, RTOT_, EMBED_, EMBED_);

    // hidden = relu(x @ W1 + b1)       (32768 x 512 x 256)
    gemm64<EP_RELU><<<dim3(FFN_ / 64, RTOT_ / 64), 256, 0, stream>>>(
        x, W1, b1, nullptr, hidden, RTOT_, FFN_, EMBED_);

    // y = hidden @ W2 + b2             (32768 x 256 x 512)
    gemm64<EP_NONE><<<dim3(EMBED_ / 64, RTOT_ / 64), 256, 0, stream>>>(
        hidden, W2, b2, nullptr, ybuf, RTOT_, EMBED_, FFN_);

    // out = x + layernorm(y)*gamma + beta
    ln_add<<<RTOT_ / 4, 256, 0, stream>>>(ybuf, gamma, beta, x);
}

// Round 2
// 212.939 us; speedup vs baseline: 2.4980x; 2.4980x over previous
//
#include <hip/hip_runtime.h>
#include <hip/hip_bf16.h>
#include <cstddef>
#include <cstdint>

#define B_      2
#define QD_     128
#define NQ_     (QD_ * QD_)          // 16384
#define EMBED_  256
#define HEADS_  8
#define POINTS_ 4
#define FFN_    512
#define RTOT_   (B_ * NQ_)           // 32768
#define NCATP_  384                  // 352 real cols padded to 384

using bf16x8 = __attribute__((ext_vector_type(8))) short;   // 8 bf16 = 4 VGPRs
using f32x4  = __attribute__((ext_vector_type(4))) float;   // MFMA accumulator

__device__ __forceinline__ short f2bf(float f) {
    unsigned u = __float_as_uint(f);
    u += 0x7FFFu + ((u >> 16) & 1u);          // round-to-nearest-even
    return (short)(u >> 16);
}

// ---------------------------------------------------------------------------
// Weight prep: transpose all weights into Bt[N][K] bf16; build padded fused
// proj weight (W_val|W_off|W_attn -> 384 cols, zero pad) and its f32 bias.
// ---------------------------------------------------------------------------
#define WCAT_ELEMS  (NCATP_ * 256)                       // 98304
#define WOUT_ELEMS  (256 * 256)                          // 65536
#define W1_ELEMS    (512 * 256)                          // 131072
#define W2_ELEMS    (256 * 512)                          // 131072
#define PREP_TOTAL  (WCAT_ELEMS + WOUT_ELEMS + W1_ELEMS + W2_ELEMS)  // 425984

__global__ __launch_bounds__(256) void prep_weights(
        const float* __restrict__ Wv, const float* __restrict__ Wo,
        const float* __restrict__ Wa, const float* __restrict__ bv,
        const float* __restrict__ bo, const float* __restrict__ ba,
        const float* __restrict__ W_out, const float* __restrict__ W1,
        const float* __restrict__ W2,
        short* __restrict__ WcatT, short* __restrict__ WoutT,
        short* __restrict__ W1T, short* __restrict__ W2T,
        float* __restrict__ bcat) {
    int idx = blockIdx.x * 256 + threadIdx.x;
    if (idx < WCAT_ELEMS) {
        int c = idx >> 8, k = idx & 255;
        float v = 0.f;
        if (c < 256)      v = Wv[k * 256 + c];
        else if (c < 320) v = Wo[k * 64 + (c - 256)];
        else if (c < 352) v = Wa[k * 32 + (c - 320)];
        WcatT[idx] = f2bf(v);
    } else if (idx < WCAT_ELEMS + WOUT_ELEMS) {
        int j = idx - WCAT_ELEMS; int c = j >> 8, k = j & 255;
        WoutT[j] = f2bf(W_out[k * 256 + c]);
    } else if (idx < WCAT_ELEMS + WOUT_ELEMS + W1_ELEMS) {
        int j = idx - (WCAT_ELEMS + WOUT_ELEMS); int c = j >> 8, k = j & 255;
        W1T[j] = f2bf(W1[k * 512 + c]);
    } else if (idx < PREP_TOTAL) {
        int j = idx - (WCAT_ELEMS + WOUT_ELEMS + W1_ELEMS); int c = j >> 9, k = j & 511;
        W2T[j] = f2bf(W2[k * 256 + c]);
    }
    if (idx < NCATP_) {
        float v = 0.f;
        if (idx < 256)      v = bv[idx];
        else if (idx < 320) v = bo[idx - 256];
        else if (idx < 352) v = ba[idx - 320];
        bcat[idx] = v;
    }
}

// ---------------------------------------------------------------------------
// bf16 MFMA GEMM: C[M,N] = A[M,K] @ Bt[N,K]^T + bias[N]  (+ epilogue)
// BM=128, BN=128, BK=64, 256 threads = 4 waves in 2x2, 64x64 per wave,
// 16x16x32 MFMA, XOR-swizzled LDS (slot ^= row&7 on 16B chunks).
// M % 128 == 0, N % 128 == 0, K % 64 == 0.
// ---------------------------------------------------------------------------
enum { EP_F32 = 0, EP_RELU_BF16 = 1, EP_ADD2Q_BOTH = 2 };

template <int EP, bool AF32>
__global__ __launch_bounds__(256) void gemm_mfma(
        const void* __restrict__ Aptr,          // [M][K] f32 (AF32) or bf16
        const short* __restrict__ Bt,           // [N][K] bf16
        const float* __restrict__ bias,         // [N]
        const float* __restrict__ extra,        // q (ADD2Q) else nullptr
        float* __restrict__ Cf,                 // f32 out or nullptr
        short* __restrict__ Cb,                 // bf16 out or nullptr
        int M, int N, int K) {
    __shared__ short As[128 * 64];
    __shared__ short Bs[128 * 64];

    const int t    = threadIdx.x;
    const int ln   = t & 63;
    const int w    = t >> 6;
    const int wr   = w >> 1;            // wave row (0..1)
    const int wc   = w & 1;             // wave col (0..1)
    const int lrow = ln & 15;
    const int lkg  = ln >> 4;           // k-group 0..3
    const int row0 = blockIdx.y * 128;
    const int col0 = blockIdx.x * 128;

    f32x4 acc[4][4] = {};

    for (int k0 = 0; k0 < K; k0 += 64) {
        // ---- stage A and B tiles (1024 chunks of 8 bf16 each) ----
        #pragma unroll
        for (int j = 0; j < 4; ++j) {
            const int c = t + 256 * j;          // chunk id 0..1023
            const int r = c >> 3;               // tile row / tile col
            const int s = c & 7;                // 16B chunk within row
            const int ss = (s ^ (r & 7)) * 8;   // swizzled slot (elems)
            // A chunk
            if (AF32) {
                const float* ap = (const float*)Aptr + (size_t)(row0 + r) * K + k0 + s * 8;
                const float4 f0 = *(const float4*)ap;
                const float4 f1 = *(const float4*)(ap + 4);
                bf16x8 v;
                v[0] = f2bf(f0.x); v[1] = f2bf(f0.y); v[2] = f2bf(f0.z); v[3] = f2bf(f0.w);
                v[4] = f2bf(f1.x); v[5] = f2bf(f1.y); v[6] = f2bf(f1.z); v[7] = f2bf(f1.w);
                *(bf16x8*)&As[r * 64 + ss] = v;
            } else {
                *(bf16x8*)&As[r * 64 + ss] =
                    *(const bf16x8*)((const short*)Aptr + (size_t)(row0 + r) * K + k0 + s * 8);
            }
            // B chunk (Bt row-major [N][K])
            *(bf16x8*)&Bs[r * 64 + ss] =
                *(const bf16x8*)(Bt + (size_t)(col0 + r) * K + k0 + s * 8);
        }
        __syncthreads();

        // ---- compute: 2 k-substeps x 16 MFMAs ----
        #pragma unroll
        for (int ks = 0; ks < 2; ++ks) {
            const int slot = ((ks * 4 + lkg) ^ (lrow & 7)) * 8;
            bf16x8 af[4], bfr[4];
            #pragma unroll
            for (int m = 0; m < 4; ++m)
                af[m] = *(const bf16x8*)&As[(wr * 64 + m * 16 + lrow) * 64 + slot];
            #pragma unroll
            for (int n = 0; n < 4; ++n)
                bfr[n] = *(const bf16x8*)&Bs[(wc * 64 + n * 16 + lrow) * 64 + slot];
            #pragma unroll
            for (int m = 0; m < 4; ++m)
                #pragma unroll
                for (int n = 0; n < 4; ++n)
                    acc[m][n] = __builtin_amdgcn_mfma_f32_16x16x32_bf16(
                        af[m], bfr[n], acc[m][n], 0, 0, 0);
        }
        __syncthreads();
    }

    // ---- epilogue: C/D mapping col=ln&15, row=(ln>>4)*4+reg ----
    const int orow = (ln >> 4) * 4;
    const int ocol = ln & 15;
    #pragma unroll
    for (int m = 0; m < 4; ++m) {
        #pragma unroll
        for (int n = 0; n < 4; ++n) {
            const int col = col0 + wc * 64 + n * 16 + ocol;
            const float bv = bias[col];
            #pragma unroll
            for (int rr = 0; rr < 4; ++rr) {
                const int row = row0 + wr * 64 + m * 16 + orow + rr;
                const size_t off = (size_t)row * N + col;
                float v = acc[m][n][rr] + bv;
                if (EP == EP_RELU_BF16) {
                    v = fmaxf(v, 0.f);
                    Cb[off] = f2bf(v);
                } else if (EP == EP_ADD2Q_BOTH) {
                    v += 2.f * extra[off];
                    Cf[off] = v;
                    Cb[off] = f2bf(v);
                } else {
                    Cf[off] = v;
                }
            }
        }
    }
}

// ---------------------------------------------------------------------------
// MSDA sampling: block = query row r, 256 threads = (head h, dim d).
// proj row layout (stride 384): [0,256) value, [256,320) off, [320,352) attn.
// Writes bf16 msda (feeds the out-proj MFMA GEMM as A).
// ---------------------------------------------------------------------------
__global__ __launch_bounds__(256) void msda_sample(const float* __restrict__ proj,
                                                   short* __restrict__ msda) {
    const int r  = blockIdx.x;          // b*NQ + n
    const int n  = r & (NQ_ - 1);
    const int bq = r >> 14;
    const int gi = n >> 7;              // grid row (y)
    const int gj = n & 127;             // grid col (x)
    const int h  = threadIdx.x >> 5;
    const int d  = threadIdx.x & 31;

    const float* prow = proj + (size_t)r * NCATP_;

    float l0 = prow[320 + h * 4 + 0];
    float l1 = prow[320 + h * 4 + 1];
    float l2 = prow[320 + h * 4 + 2];
    float l3 = prow[320 + h * 4 + 3];
    float mx = fmaxf(fmaxf(l0, l1), fmaxf(l2, l3));
    float e0 = expf(l0 - mx), e1 = expf(l1 - mx), e2 = expf(l2 - mx), e3 = expf(l3 - mx);
    const float inv = 1.0f / (e0 + e1 + e2 + e3);
    const float aw[4] = {e0 * inv, e1 * inv, e2 * inv, e3 * inv};

    const float* vbase = proj + (size_t)bq * NQ_ * NCATP_ + h * 32 + d;

    float acc = 0.f;
    #pragma unroll
    for (int p = 0; p < 4; ++p) {
        const float ox = prow[256 + h * 8 + p * 2 + 0];
        const float oy = prow[256 + h * 8 + p * 2 + 1];
        const float px = (gj * (1.0f / 127.0f) + ox * (1.0f / 128.0f)) * 128.0f - 0.5f;
        const float py = (gi * (1.0f / 127.0f) + oy * (1.0f / 128.0f)) * 128.0f - 0.5f;
        const float x0f = floorf(px), y0f = floorf(py);
        const int   x0 = (int)x0f, y0 = (int)y0f;
        const float fx = px - x0f, fy = py - y0f;
        const float w00 = (1.f - fx) * (1.f - fy);
        const float w01 = fx * (1.f - fy);
        const float w10 = (1.f - fx) * fy;
        const float w11 = fx * fy;

        float s = 0.f;
        const int x1 = x0 + 1, y1 = y0 + 1;
        if (((unsigned)x0 <= 127u) & ((unsigned)y0 <= 127u))
            s += w00 * vbase[(size_t)(y0 * 128 + x0) * NCATP_];
        if (((unsigned)x1 <= 127u) & ((unsigned)y0 <= 127u))
            s += w01 * vbase[(size_t)(y0 * 128 + x1) * NCATP_];
        if (((unsigned)x0 <= 127u) & ((unsigned)y1 <= 127u))
            s += w10 * vbase[(size_t)(y1 * 128 + x0) * NCATP_];
        if (((unsigned)x1 <= 127u) & ((unsigned)y1 <= 127u))
            s += w11 * vbase[(size_t)(y1 * 128 + x1) * NCATP_];

        acc += aw[p] * s;
    }
    msda[(size_t)r * EMBED_ + h * 32 + d] = f2bf(acc);
}

// ---------------------------------------------------------------------------
// out = x + layernorm(y)*gamma + beta   (x lives in d_out, updated in place)
// ---------------------------------------------------------------------------
__global__ __launch_bounds__(256) void ln_add(const float* __restrict__ y,
                                              const float* __restrict__ gamma,
                                              const float* __restrict__ beta,
                                              float* __restrict__ xout) {
    const int wave = threadIdx.x >> 6;
    const int lane = threadIdx.x & 63;
    const size_t row = (size_t)blockIdx.x * 4 + wave;

    const float4 yv = *(const float4*)(y + row * EMBED_ + lane * 4);
    float s  = yv.x + yv.y + yv.z + yv.w;
    float sq = yv.x * yv.x + yv.y * yv.y + yv.z * yv.z + yv.w * yv.w;
    #pragma unroll
    for (int o = 32; o; o >>= 1) {
        s  += __shfl_xor(s, o, 64);
        sq += __shfl_xor(sq, o, 64);
    }
    const float m   = s * (1.0f / EMBED_);
    const float var = sq * (1.0f / EMBED_) - m * m;
    const float rs  = rsqrtf(var + 1e-5f);

    const float4 xv = *(const float4*)(xout + row * EMBED_ + lane * 4);
    const float4 g  = *(const float4*)(gamma + lane * 4);
    const float4 bt = *(const float4*)(beta + lane * 4);
    float4 o4;
    o4.x = xv.x + (yv.x - m) * rs * g.x + bt.x;
    o4.y = xv.y + (yv.y - m) * rs * g.y + bt.y;
    o4.z = xv.z + (yv.z - m) * rs * g.z + bt.z;
    o4.w = xv.w + (yv.w - m) * rs * g.w + bt.w;
    *(float4*)(xout + row * EMBED_ + lane * 4) = o4;
}

// ---------------------------------------------------------------------------
extern "C" void kernel_launch(void* const* d_in, const int* in_sizes, int n_in,
                              void* d_out, int out_size, void* d_ws, size_t ws_size,
                              hipStream_t stream) {
    const float* q      = (const float*)d_in[0];
    const float* W_off  = (const float*)d_in[1];
    const float* b_off  = (const float*)d_in[2];
    const float* W_attn = (const float*)d_in[3];
    const float* b_attn = (const float*)d_in[4];
    const float* W_val  = (const float*)d_in[5];
    const float* b_val  = (const float*)d_in[6];
    const float* W_out  = (const float*)d_in[7];
    const float* b_out  = (const float*)d_in[8];
    const float* W1     = (const float*)d_in[9];
    const float* b1     = (const float*)d_in[10];
    const float* W2     = (const float*)d_in[11];
    const float* b2     = (const float*)d_in[12];
    const float* gamma  = (const float*)d_in[13];
    const float* beta   = (const float*)d_in[14];

    float* x = (float*)d_out;

    char* w = (char*)d_ws;
    float* proj  = (float*)w;                       // 32768*384*4 = 50,331,648 B
    float* ybuf  = proj;                            // overlaps (proj dead after sampler)
    w += (size_t)RTOT_ * NCATP_ * 4;
    short* msda  = (short*)w; w += (size_t)RTOT_ * EMBED_ * 2;   // 16.8 MB
    short* xbf   = (short*)w; w += (size_t)RTOT_ * EMBED_ * 2;   // 16.8 MB
    short* hid   = (short*)w; w += (size_t)RTOT_ * FFN_ * 2;     // 33.6 MB
    short* WcatT = (short*)w; w += WCAT_ELEMS * 2;
    short* WoutT = (short*)w; w += WOUT_ELEMS * 2;
    short* W1T   = (short*)w; w += W1_ELEMS * 2;
    short* W2T   = (short*)w; w += W2_ELEMS * 2;
    float* bcat  = (float*)w; w += NCATP_ * 4;

    prep_weights<<<(PREP_TOTAL + 255) / 256, 256, 0, stream>>>(
        W_val, W_off, W_attn, b_val, b_off, b_attn, W_out, W1, W2,
        WcatT, WoutT, W1T, W2T, bcat);

    // proj = q @ Wcat + bcat            (32768 x 384 x 256), A = f32 q
    gemm_mfma<EP_F32, true><<<dim3(NCATP_ / 128, RTOT_ / 128), 256, 0, stream>>>(
        q, WcatT, bcat, nullptr, proj, nullptr, RTOT_, NCATP_, EMBED_);

    // MSDA sampling -> msda (bf16)
    msda_sample<<<RTOT_, 256, 0, stream>>>(proj, msda);

    // x = msda @ W_out + b_out + 2q     (32768 x 256 x 256); also x -> bf16
    gemm_mfma<EP_ADD2Q_BOTH, false><<<dim3(EMBED_ / 128, RTOT_ / 128), 256, 0, stream>>>(
        msda, WoutT, b_out, q, x, xbf, RTOT_, EMBED_, EMBED_);

    // hidden = relu(x @ W1 + b1)        (32768 x 512 x 256), bf16 out
    gemm_mfma<EP_RELU_BF16, false><<<dim3(FFN_ / 128, RTOT_ / 128), 256, 0, stream>>>(
        xbf, W1T, b1, nullptr, nullptr, hid, RTOT_, FFN_, EMBED_);

    // y = hidden @ W2 + b2              (32768 x 256 x 512), f32 out
    gemm_mfma<EP_F32, false><<<dim3(EMBED_ / 128, RTOT_ / 128), 256, 0, stream>>>(
        hid, W2T, b2, nullptr, ybuf, nullptr, RTOT_, EMBED_, FFN_);

    // out = x + layernorm(y)*gamma + beta
    ln_add<<<RTOT_ / 4, 256, 0, stream>>>(ybuf, gamma, beta, x);
}

// Round 3
// 126.222 us; speedup vs baseline: 4.2141x; 1.6870x over previous
//
#include <hip/hip_runtime.h>
#include <hip/hip_bf16.h>
#include <cstddef>
#include <cstdint>

#define B_      2
#define QD_     128
#define NQ_     (QD_ * QD_)          // 16384
#define EMBED_  256
#define HEADS_  8
#define POINTS_ 4
#define FFN_    512
#define RTOT_   (B_ * NQ_)           // 32768
#define NCATP_  384                  // 352 real cols padded to 384

using bf16x8 = __attribute__((ext_vector_type(8))) short;   // 8 bf16 = 4 VGPRs
using f32x4  = __attribute__((ext_vector_type(4))) float;   // MFMA accumulator

__device__ __forceinline__ short f2bf(float f) {
    unsigned u = __float_as_uint(f);
    u += 0x7FFFu + ((u >> 16) & 1u);          // round-to-nearest-even
    return (short)(u >> 16);
}

// ---------------------------------------------------------------------------
// Weight prep: transpose weights into Bt[N][K] bf16; padded fused proj weight.
// ---------------------------------------------------------------------------
#define WCAT_ELEMS  (NCATP_ * 256)                       // 98304
#define WOUT_ELEMS  (256 * 256)
#define W1_ELEMS    (512 * 256)
#define W2_ELEMS    (256 * 512)
#define PREP_TOTAL  (WCAT_ELEMS + WOUT_ELEMS + W1_ELEMS + W2_ELEMS)

__global__ __launch_bounds__(256) void prep_weights(
        const float* __restrict__ Wv, const float* __restrict__ Wo,
        const float* __restrict__ Wa, const float* __restrict__ bv,
        const float* __restrict__ bo, const float* __restrict__ ba,
        const float* __restrict__ W_out, const float* __restrict__ W1,
        const float* __restrict__ W2,
        short* __restrict__ WcatT, short* __restrict__ WoutT,
        short* __restrict__ W1T, short* __restrict__ W2T,
        float* __restrict__ bcat) {
    int idx = blockIdx.x * 256 + threadIdx.x;
    if (idx < WCAT_ELEMS) {
        int c = idx >> 8, k = idx & 255;
        float v = 0.f;
        if (c < 256)      v = Wv[k * 256 + c];
        else if (c < 320) v = Wo[k * 64 + (c - 256)];
        else if (c < 352) v = Wa[k * 32 + (c - 320)];
        WcatT[idx] = f2bf(v);
    } else if (idx < WCAT_ELEMS + WOUT_ELEMS) {
        int j = idx - WCAT_ELEMS; int c = j >> 8, k = j & 255;
        WoutT[j] = f2bf(W_out[k * 256 + c]);
    } else if (idx < WCAT_ELEMS + WOUT_ELEMS + W1_ELEMS) {
        int j = idx - (WCAT_ELEMS + WOUT_ELEMS); int c = j >> 8, k = j & 255;
        W1T[j] = f2bf(W1[k * 512 + c]);
    } else if (idx < PREP_TOTAL) {
        int j = idx - (WCAT_ELEMS + WOUT_ELEMS + W1_ELEMS); int c = j >> 9, k = j & 511;
        W2T[j] = f2bf(W2[k * 256 + c]);
    }
    if (idx < NCATP_) {
        float v = 0.f;
        if (idx < 256)      v = bv[idx];
        else if (idx < 320) v = bo[idx - 256];
        else if (idx < 352) v = ba[idx - 320];
        bcat[idx] = v;
    }
}

// ---------------------------------------------------------------------------
// f32 -> bf16 elementwise (8 per thread)
// ---------------------------------------------------------------------------
__global__ __launch_bounds__(256) void cvt_bf16(const float* __restrict__ in,
                                                short* __restrict__ out) {
    const size_t i = (size_t)blockIdx.x * 256 + threadIdx.x;
    const float4 f0 = *(const float4*)(in + i * 8);
    const float4 f1 = *(const float4*)(in + i * 8 + 4);
    bf16x8 v;
    v[0] = f2bf(f0.x); v[1] = f2bf(f0.y); v[2] = f2bf(f0.z); v[3] = f2bf(f0.w);
    v[4] = f2bf(f1.x); v[5] = f2bf(f1.y); v[6] = f2bf(f1.z); v[7] = f2bf(f1.w);
    *(bf16x8*)(out + i * 8) = v;
}

// ---------------------------------------------------------------------------
// bf16 MFMA GEMM: C[M,N] = A[M,K] @ Bt[N,K]^T + bias[N]  (+ epilogue)
// BM=BN=128, BK=64, 4 waves (2x2), 64x64/wave, 16x16x32 MFMA.
// Staging: global_load_lds width=16, pre-swizzled SOURCE + linear LDS dest,
// XOR swizzle (slot ^= row&7 on 16B chunks) applied on the read side.
// ---------------------------------------------------------------------------
enum { EP_F32 = 0, EP_RELU_BF16 = 1, EP_ADD2Q_BOTH = 2, EP_SPLIT = 3 };

template <int EP>
__global__ __launch_bounds__(256) void gemm_mfma(
        const short* __restrict__ A,            // [M][K] bf16
        const short* __restrict__ Bt,           // [N][K] bf16
        const float* __restrict__ bias,         // [N]
        const float* __restrict__ extra,        // q (ADD2Q) else nullptr
        float* __restrict__ Cf,                 // f32 out (or pm for SPLIT)
        short* __restrict__ Cb,                 // bf16 out (or vcomp for SPLIT)
        int M, int N, int K) {
    __shared__ __align__(16) short As[128 * 64];
    __shared__ __align__(16) short Bs[128 * 64];

    const int t    = threadIdx.x;
    const int ln   = t & 63;
    const int w    = t >> 6;
    const int wr   = w >> 1;
    const int wc   = w & 1;
    const int lrow = ln & 15;
    const int lkg  = ln >> 4;
    const int row0 = blockIdx.y * 128;
    const int col0 = blockIdx.x * 128;

    f32x4 acc[4][4] = {};

    for (int k0 = 0; k0 < K; k0 += 64) {
        // ---- stage via global_load_lds (wave-uniform LDS base + lane*16) ----
        #pragma unroll
        for (int j = 0; j < 4; ++j) {
            const int c0 = (w * 4 + j) * 64;        // wave-uniform chunk base
            const int c  = c0 + ln;                 // this lane's chunk
            const int r  = c >> 3;
            const int s  = (c & 7) ^ (r & 7);       // pre-swizzled source chunk
            const short* ga = A  + (size_t)(row0 + r) * K + (k0 + s * 8);
            const short* gb = Bt + (size_t)(col0 + r) * K + (k0 + s * 8);
            __builtin_amdgcn_global_load_lds(
                (const __attribute__((address_space(1))) void*)ga,
                (__attribute__((address_space(3))) void*)&As[c0 * 8], 16, 0, 0);
            __builtin_amdgcn_global_load_lds(
                (const __attribute__((address_space(1))) void*)gb,
                (__attribute__((address_space(3))) void*)&Bs[c0 * 8], 16, 0, 0);
        }
        __syncthreads();

        // ---- compute: 2 k-substeps x 16 MFMAs ----
        #pragma unroll
        for (int ks = 0; ks < 2; ++ks) {
            const int slot = ((ks * 4 + lkg) ^ (lrow & 7)) * 8;
            bf16x8 af[4], bfr[4];
            #pragma unroll
            for (int m = 0; m < 4; ++m)
                af[m] = *(const bf16x8*)&As[(wr * 64 + m * 16 + lrow) * 64 + slot];
            #pragma unroll
            for (int n = 0; n < 4; ++n)
                bfr[n] = *(const bf16x8*)&Bs[(wc * 64 + n * 16 + lrow) * 64 + slot];
            #pragma unroll
            for (int m = 0; m < 4; ++m)
                #pragma unroll
                for (int n = 0; n < 4; ++n)
                    acc[m][n] = __builtin_amdgcn_mfma_f32_16x16x32_bf16(
                        af[m], bfr[n], acc[m][n], 0, 0, 0);
        }
        __syncthreads();
    }

    // ---- epilogue: C/D mapping col=ln&15, row=(ln>>4)*4+reg ----
    const int orow = (ln >> 4) * 4;
    const int ocol = ln & 15;
    #pragma unroll
    for (int m = 0; m < 4; ++m) {
        #pragma unroll
        for (int n = 0; n < 4; ++n) {
            const int col = col0 + wc * 64 + n * 16 + ocol;
            const float bv = bias[col];
            #pragma unroll
            for (int rr = 0; rr < 4; ++rr) {
                const int row = row0 + wr * 64 + m * 16 + orow + rr;
                float v = acc[m][n][rr] + bv;
                if (EP == EP_SPLIT) {
                    if (col < 256) Cb[(size_t)row * 256 + col] = f2bf(v);
                    else           Cf[(size_t)row * 128 + (col - 256)] = v;
                } else if (EP == EP_RELU_BF16) {
                    Cb[(size_t)row * N + col] = f2bf(fmaxf(v, 0.f));
                } else if (EP == EP_ADD2Q_BOTH) {
                    v += 2.f * extra[(size_t)row * N + col];
                    Cf[(size_t)row * N + col] = v;
                    Cb[(size_t)row * N + col] = f2bf(v);
                } else {
                    Cf[(size_t)row * N + col] = v;
                }
            }
        }
    }
}

// ---------------------------------------------------------------------------
// MSDA sampler, two-phase.
// pm[r][128]: [0,64) offsets (h*8+p*2+{x,y}), [64,96) attn logits, pad.
// vcomp[b*NQ+idx][256] bf16 value, col = h*32+d.
// Phase 1: 256 threads = 8 queries x (h,p): weights+byteoffsets -> LDS.
// Phase 2: 128 threads/query = (h, dpair): 16 dword gathers, 2 bf16 each.
// ---------------------------------------------------------------------------
__global__ __launch_bounds__(256) void msda_sample(
        const float* __restrict__ pm, const short* __restrict__ vcomp,
        short* __restrict__ msda) {
    __shared__ int   s_off[8][32][4];
    __shared__ float s_c[8][32][4];

    const int t  = threadIdx.x;
    const int r0 = blockIdx.x * 8;
    const int bq = r0 >> 14;

    // ---- phase 1 ----
    {
        const int g = t >> 5, cmb = t & 31, h = cmb >> 2, p = cmb & 3;
        const int r = r0 + g;
        const int n = r & (NQ_ - 1);
        const int gi = n >> 7, gj = n & 127;
        const float* pr = pm + (size_t)r * 128;

        const float l0 = pr[64 + h * 4 + 0], l1 = pr[64 + h * 4 + 1];
        const float l2 = pr[64 + h * 4 + 2], l3 = pr[64 + h * 4 + 3];
        const float mx = fmaxf(fmaxf(l0, l1), fmaxf(l2, l3));
        const float sum = expf(l0 - mx) + expf(l1 - mx) + expf(l2 - mx) + expf(l3 - mx);
        const float lp = pr[64 + h * 4 + p];
        const float aw = expf(lp - mx) / sum;

        const float ox = pr[h * 8 + p * 2 + 0];
        const float oy = pr[h * 8 + p * 2 + 1];
        const float px = (gj * (1.0f / 127.0f) + ox * (1.0f / 128.0f)) * 128.0f - 0.5f;
        const float py = (gi * (1.0f / 127.0f) + oy * (1.0f / 128.0f)) * 128.0f - 0.5f;
        const float x0f = floorf(px), y0f = floorf(py);
        const int   x0 = (int)x0f, y0 = (int)y0f;
        const float fx = px - x0f, fy = py - y0f;
        const int x0c = min(max(x0, 0), 127), x1c = min(max(x0 + 1, 0), 127);
        const int y0c = min(max(y0, 0), 127), y1c = min(max(y0 + 1, 0), 127);
        const float vx0 = ((unsigned)x0 <= 127u) ? 1.f : 0.f;
        const float vx1 = ((unsigned)(x0 + 1) <= 127u) ? 1.f : 0.f;
        const float vy0 = ((unsigned)y0 <= 127u) ? 1.f : 0.f;
        const float vy1 = ((unsigned)(y0 + 1) <= 127u) ? 1.f : 0.f;

        s_off[g][cmb][0] = (y0c * 128 + x0c) * 512;   // byte offset (512 B/row)
        s_off[g][cmb][1] = (y0c * 128 + x1c) * 512;
        s_off[g][cmb][2] = (y1c * 128 + x0c) * 512;
        s_off[g][cmb][3] = (y1c * 128 + x1c) * 512;
        s_c[g][cmb][0] = aw * (1.f - fx) * (1.f - fy) * vx0 * vy0;
        s_c[g][cmb][1] = aw * fx * (1.f - fy) * vx1 * vy0;
        s_c[g][cmb][2] = aw * (1.f - fx) * fy * vx0 * vy1;
        s_c[g][cmb][3] = aw * fx * fy * vx1 * vy1;
    }
    __syncthreads();

    // ---- phase 2 ----
    const int half = t >> 7;
    const int h    = (t >> 4) & 7;
    const int dd   = t & 15;
    const char* vb = (const char*)vcomp + ((size_t)bq * NQ_ * 256 + h * 32 + dd * 2) * 2;

    #pragma unroll
    for (int it = 0; it < 4; ++it) {
        const int g = it * 2 + half;
        float a0 = 0.f, a1 = 0.f;
        #pragma unroll
        for (int p = 0; p < 4; ++p) {
            const int cmb = h * 4 + p;
            #pragma unroll
            for (int k = 0; k < 4; ++k) {
                const unsigned u = *(const unsigned*)(vb + s_off[g][cmb][k]);
                const float c = s_c[g][cmb][k];
                a0 += c * __uint_as_float(u << 16);
                a1 += c * __uint_as_float(u & 0xffff0000u);
            }
        }
        const int r = r0 + g;
        const unsigned o = (unsigned)(unsigned short)f2bf(a0)
                         | ((unsigned)(unsigned short)f2bf(a1) << 16);
        *(unsigned*)&msda[(size_t)r * 256 + h * 32 + dd * 2] = o;
    }
}

// ---------------------------------------------------------------------------
// out = x + layernorm(y)*gamma + beta   (x in d_out, updated in place)
// ---------------------------------------------------------------------------
__global__ __launch_bounds__(256) void ln_add(const float* __restrict__ y,
                                              const float* __restrict__ gamma,
                                              const float* __restrict__ beta,
                                              float* __restrict__ xout) {
    const int wave = threadIdx.x >> 6;
    const int lane = threadIdx.x & 63;
    const size_t row = (size_t)blockIdx.x * 4 + wave;

    const float4 yv = *(const float4*)(y + row * EMBED_ + lane * 4);
    float s  = yv.x + yv.y + yv.z + yv.w;
    float sq = yv.x * yv.x + yv.y * yv.y + yv.z * yv.z + yv.w * yv.w;
    #pragma unroll
    for (int o = 32; o; o >>= 1) {
        s  += __shfl_xor(s, o, 64);
        sq += __shfl_xor(sq, o, 64);
    }
    const float m   = s * (1.0f / EMBED_);
    const float var = sq * (1.0f / EMBED_) - m * m;
    const float rs  = rsqrtf(var + 1e-5f);

    const float4 xv = *(const float4*)(xout + row * EMBED_ + lane * 4);
    const float4 g  = *(const float4*)(gamma + lane * 4);
    const float4 bt = *(const float4*)(beta + lane * 4);
    float4 o4;
    o4.x = xv.x + (yv.x - m) * rs * g.x + bt.x;
    o4.y = xv.y + (yv.y - m) * rs * g.y + bt.y;
    o4.z = xv.z + (yv.z - m) * rs * g.z + bt.z;
    o4.w = xv.w + (yv.w - m) * rs * g.w + bt.w;
    *(float4*)(xout + row * EMBED_ + lane * 4) = o4;
}

// ---------------------------------------------------------------------------
extern "C" void kernel_launch(void* const* d_in, const int* in_sizes, int n_in,
                              void* d_out, int out_size, void* d_ws, size_t ws_size,
                              hipStream_t stream) {
    const float* q      = (const float*)d_in[0];
    const float* b_out  = (const float*)d_in[8];
    const float* b1     = (const float*)d_in[10];
    const float* b2     = (const float*)d_in[12];
    const float* gamma  = (const float*)d_in[13];
    const float* beta   = (const float*)d_in[14];

    float* x = (float*)d_out;

    char* w = (char*)d_ws;
    float* pm    = (float*)w;                                   // 16.8 MB
    short* vcomp = (short*)(w + (size_t)RTOT_ * 128 * 4);       // 16.8 MB
    float* ybuf  = (float*)w;                                   // overlaps pm+vcomp
    w += (size_t)RTOT_ * 128 * 4 + (size_t)RTOT_ * 256 * 2;     // 33.6 MB
    short* qbf  = (short*)w; w += (size_t)RTOT_ * EMBED_ * 2;   // 16.8 MB
    short* msda = (short*)w; w += (size_t)RTOT_ * EMBED_ * 2;   // 16.8 MB
    short* xbf  = (short*)w; w += (size_t)RTOT_ * EMBED_ * 2;   // 16.8 MB
    short* hid  = (short*)w; w += (size_t)RTOT_ * FFN_ * 2;     // 33.6 MB
    short* WcatT = (short*)w; w += WCAT_ELEMS * 2;
    short* WoutT = (short*)w; w += WOUT_ELEMS * 2;
    short* W1T   = (short*)w; w += W1_ELEMS * 2;
    short* W2T   = (short*)w; w += W2_ELEMS * 2;
    float* bcat  = (float*)w; w += NCATP_ * 4;

    prep_weights<<<(PREP_TOTAL + 255) / 256, 256, 0, stream>>>(
        q /*unused*/ == nullptr ? nullptr : (const float*)d_in[5], // W_val
        (const float*)d_in[1], (const float*)d_in[3],
        (const float*)d_in[6], (const float*)d_in[2], (const float*)d_in[4],
        (const float*)d_in[7], (const float*)d_in[9], (const float*)d_in[11],
        WcatT, WoutT, W1T, W2T, bcat);

    // q -> bf16
    cvt_bf16<<<(RTOT_ * EMBED_ / 8 + 255) / 256, 256, 0, stream>>>(q, qbf);

    // proj: vcomp (bf16 value) + pm (f32 meta)   (32768 x 384 x 256)
    gemm_mfma<EP_SPLIT><<<dim3(NCATP_ / 128, RTOT_ / 128), 256, 0, stream>>>(
        qbf, WcatT, bcat, nullptr, pm, vcomp, RTOT_, NCATP_, EMBED_);

    // MSDA sampling -> msda (bf16)
    msda_sample<<<RTOT_ / 8, 256, 0, stream>>>(pm, vcomp, msda);

    // x = msda @ W_out + b_out + 2q   (32768 x 256 x 256); also bf16 copy
    gemm_mfma<EP_ADD2Q_BOTH><<<dim3(EMBED_ / 128, RTOT_ / 128), 256, 0, stream>>>(
        msda, WoutT, b_out, q, x, xbf, RTOT_, EMBED_, EMBED_);

    // hidden = relu(x @ W1 + b1)      (32768 x 512 x 256), bf16
    gemm_mfma<EP_RELU_BF16><<<dim3(FFN_ / 128, RTOT_ / 128), 256, 0, stream>>>(
        xbf, W1T, b1, nullptr, nullptr, hid, RTOT_, FFN_, EMBED_);

    // y = hidden @ W2 + b2            (32768 x 256 x 512), f32
    gemm_mfma<EP_F32><<<dim3(EMBED_ / 128, RTOT_ / 128), 256, 0, stream>>>(
        hid, W2T, b2, nullptr, ybuf, nullptr, RTOT_, EMBED_, FFN_);

    // out = x + layernorm(y)*gamma + beta
    ln_add<<<RTOT_ / 4, 256, 0, stream>>>(ybuf, gamma, beta, x);
}

// Round 4
// 107.459 us; speedup vs baseline: 4.9500x; 1.1746x over previous
//
#include <hip/hip_runtime.h>
#include <hip/hip_bf16.h>
#include <cstddef>
#include <cstdint>

#define B_      2
#define QD_     128
#define NQ_     (QD_ * QD_)          // 16384
#define EMBED_  256
#define HEADS_  8
#define POINTS_ 4
#define FFN_    512
#define RTOT_   (B_ * NQ_)           // 32768
#define NCATP_  384                  // 352 real cols padded to 384

using bf16x8 = __attribute__((ext_vector_type(8))) short;   // 8 bf16 = 4 VGPRs
using f32x4  = __attribute__((ext_vector_type(4))) float;   // MFMA accumulator

__device__ __forceinline__ short f2bf(float f) {
    unsigned u = __float_as_uint(f);
    u += 0x7FFFu + ((u >> 16) & 1u);          // round-to-nearest-even
    return (short)(u >> 16);
}
__device__ __forceinline__ float bf2f(short s) {
    return __uint_as_float(((unsigned)(unsigned short)s) << 16);
}

// ---------------------------------------------------------------------------
// Weight prep: transpose weights into Bt[N][K] bf16; padded fused proj weight.
// ---------------------------------------------------------------------------
#define WCAT_ELEMS  (NCATP_ * 256)
#define WOUT_ELEMS  (256 * 256)
#define W1_ELEMS    (512 * 256)
#define W2_ELEMS    (256 * 512)
#define PREP_TOTAL  (WCAT_ELEMS + WOUT_ELEMS + W1_ELEMS + W2_ELEMS)

__global__ __launch_bounds__(256) void prep_weights(
        const float* __restrict__ Wv, const float* __restrict__ Wo,
        const float* __restrict__ Wa, const float* __restrict__ bv,
        const float* __restrict__ bo, const float* __restrict__ ba,
        const float* __restrict__ W_out, const float* __restrict__ W1,
        const float* __restrict__ W2,
        short* __restrict__ WcatT, short* __restrict__ WoutT,
        short* __restrict__ W1T, short* __restrict__ W2T,
        float* __restrict__ bcat) {
    int idx = blockIdx.x * 256 + threadIdx.x;
    if (idx < WCAT_ELEMS) {
        int c = idx >> 8, k = idx & 255;
        float v = 0.f;
        if (c < 256)      v = Wv[k * 256 + c];
        else if (c < 320) v = Wo[k * 64 + (c - 256)];
        else if (c < 352) v = Wa[k * 32 + (c - 320)];
        WcatT[idx] = f2bf(v);
    } else if (idx < WCAT_ELEMS + WOUT_ELEMS) {
        int j = idx - WCAT_ELEMS; int c = j >> 8, k = j & 255;
        WoutT[j] = f2bf(W_out[k * 256 + c]);
    } else if (idx < WCAT_ELEMS + WOUT_ELEMS + W1_ELEMS) {
        int j = idx - (WCAT_ELEMS + WOUT_ELEMS); int c = j >> 8, k = j & 255;
        W1T[j] = f2bf(W1[k * 512 + c]);
    } else if (idx < PREP_TOTAL) {
        int j = idx - (WCAT_ELEMS + WOUT_ELEMS + W1_ELEMS); int c = j >> 9, k = j & 511;
        W2T[j] = f2bf(W2[k * 256 + c]);
    }
    if (idx < NCATP_) {
        float v = 0.f;
        if (idx < 256)      v = bv[idx];
        else if (idx < 320) v = bo[idx - 256];
        else if (idx < 352) v = ba[idx - 320];
        bcat[idx] = v;
    }
}

// ---------------------------------------------------------------------------
// f32 -> bf16 elementwise (8 per thread)
// ---------------------------------------------------------------------------
__global__ __launch_bounds__(256) void cvt_bf16(const float* __restrict__ in,
                                                short* __restrict__ out) {
    const size_t i = (size_t)blockIdx.x * 256 + threadIdx.x;
    const float4 f0 = *(const float4*)(in + i * 8);
    const float4 f1 = *(const float4*)(in + i * 8 + 4);
    bf16x8 v;
    v[0] = f2bf(f0.x); v[1] = f2bf(f0.y); v[2] = f2bf(f0.z); v[3] = f2bf(f0.w);
    v[4] = f2bf(f1.x); v[5] = f2bf(f1.y); v[6] = f2bf(f1.z); v[7] = f2bf(f1.w);
    *(bf16x8*)(out + i * 8) = v;
}

// ---------------------------------------------------------------------------
// bf16 MFMA GEMM: C = A[M,K] @ Bt[N,K]^T + bias  (+ epilogue)
// BM=BN=128, BK=64, 4 waves (2x2), 64x64/wave, 16x16x32 MFMA.
// global_load_lds w16, pre-swizzled source + linear dest, XOR-swizzled reads.
// ---------------------------------------------------------------------------
enum { EP_RELU_BF16 = 1, EP_ADD2Q_BF16 = 2, EP_SPLIT = 3 };

template <int EP>
__global__ __launch_bounds__(256) void gemm_mfma(
        const short* __restrict__ A,            // [M][K] bf16
        const short* __restrict__ Bt,           // [N][K] bf16
        const float* __restrict__ bias,         // [N]
        const short* __restrict__ extra,        // qbf (ADD2Q) else nullptr
        float* __restrict__ Cf,                 // pm (SPLIT) else nullptr
        short* __restrict__ Cb,                 // bf16 out
        int M, int N, int K) {
    __shared__ __align__(16) short As[128 * 64];
    __shared__ __align__(16) short Bs[128 * 64];

    const int t    = threadIdx.x;
    const int ln   = t & 63;
    const int w    = t >> 6;
    const int wr   = w >> 1;
    const int wc   = w & 1;
    const int lrow = ln & 15;
    const int lkg  = ln >> 4;

    // XCD-aware bijective swizzle (nwg % 8 == 0 for all our grids)
    const int gx   = gridDim.x;
    const int nwg  = gx * gridDim.y;
    const int flat = blockIdx.y * gx + blockIdx.x;
    const int q8   = nwg >> 3;
    const int swz  = (flat & 7) * q8 + (flat >> 3);
    const int row0 = (swz / gx) * 128;
    const int col0 = (swz % gx) * 128;

    f32x4 acc[4][4] = {};

    for (int k0 = 0; k0 < K; k0 += 64) {
        #pragma unroll
        for (int j = 0; j < 4; ++j) {
            const int c0 = (w * 4 + j) * 64;        // wave-uniform chunk base
            const int c  = c0 + ln;
            const int r  = c >> 3;
            const int s  = (c & 7) ^ (r & 7);       // pre-swizzled source chunk
            const short* ga = A  + (size_t)(row0 + r) * K + (k0 + s * 8);
            const short* gb = Bt + (size_t)(col0 + r) * K + (k0 + s * 8);
            __builtin_amdgcn_global_load_lds(
                (const __attribute__((address_space(1))) void*)ga,
                (__attribute__((address_space(3))) void*)&As[c0 * 8], 16, 0, 0);
            __builtin_amdgcn_global_load_lds(
                (const __attribute__((address_space(1))) void*)gb,
                (__attribute__((address_space(3))) void*)&Bs[c0 * 8], 16, 0, 0);
        }
        __syncthreads();

        #pragma unroll
        for (int ks = 0; ks < 2; ++ks) {
            const int slot = ((ks * 4 + lkg) ^ (lrow & 7)) * 8;
            bf16x8 af[4], bfr[4];
            #pragma unroll
            for (int m = 0; m < 4; ++m)
                af[m] = *(const bf16x8*)&As[(wr * 64 + m * 16 + lrow) * 64 + slot];
            #pragma unroll
            for (int n = 0; n < 4; ++n)
                bfr[n] = *(const bf16x8*)&Bs[(wc * 64 + n * 16 + lrow) * 64 + slot];
            #pragma unroll
            for (int m = 0; m < 4; ++m)
                #pragma unroll
                for (int n = 0; n < 4; ++n)
                    acc[m][n] = __builtin_amdgcn_mfma_f32_16x16x32_bf16(
                        af[m], bfr[n], acc[m][n], 0, 0, 0);
        }
        __syncthreads();
    }

    // C/D mapping: col = ln&15, row = (ln>>4)*4 + reg
    const int orow = (ln >> 4) * 4;
    const int ocol = ln & 15;
    #pragma unroll
    for (int m = 0; m < 4; ++m) {
        #pragma unroll
        for (int n = 0; n < 4; ++n) {
            const int col = col0 + wc * 64 + n * 16 + ocol;
            const float bv = bias[col];
            #pragma unroll
            for (int rr = 0; rr < 4; ++rr) {
                const int row = row0 + wr * 64 + m * 16 + orow + rr;
                float v = acc[m][n][rr] + bv;
                if (EP == EP_SPLIT) {
                    if (col < 256) Cb[(size_t)row * 256 + col] = f2bf(v);
                    else           Cf[(size_t)row * 128 + (col - 256)] = v;
                } else if (EP == EP_RELU_BF16) {
                    Cb[(size_t)row * N + col] = f2bf(fmaxf(v, 0.f));
                } else if (EP == EP_ADD2Q_BF16) {
                    v += 2.f * bf2f(extra[(size_t)row * N + col]);
                    Cb[(size_t)row * N + col] = f2bf(v);
                }
            }
        }
    }
}

// ---------------------------------------------------------------------------
// Fused W2 GEMM + LayerNorm + residual:  out = x + LN(hid@W2 + b2)*g + beta
// BM=64, BN=256 (full row per block), BK=64, 4 waves side by side (64 cols ea).
// LN stats on f32 accumulators: 16-lane shuffle reduce + LDS cross-wave.
// ---------------------------------------------------------------------------
__global__ __launch_bounds__(256) void gemm_ln(
        const short* __restrict__ A,            // hid [M][512] bf16
        const short* __restrict__ Bt,           // W2T [256][512] bf16
        const float* __restrict__ bias,         // b2
        const short* __restrict__ xres,         // xbf [M][256] bf16
        const float* __restrict__ gamma, const float* __restrict__ beta,
        float* __restrict__ out, int M, int K) {
    __shared__ __align__(16) short As[64 * 64];
    __shared__ __align__(16) short Bs[256 * 64];
    __shared__ float red[64][4][2];

    const int t    = threadIdx.x;
    const int ln   = t & 63;
    const int w    = t >> 6;
    const int lrow = ln & 15;
    const int lkg  = ln >> 4;
    const int row0 = blockIdx.x * 64;

    f32x4 acc[4][4] = {};

    for (int k0 = 0; k0 < K; k0 += 64) {
        // A: 512 chunks (2/thread), B: 2048 chunks (8/thread)
        #pragma unroll
        for (int j = 0; j < 2; ++j) {
            const int c0 = (w * 2 + j) * 64;
            const int c  = c0 + ln;
            const int r  = c >> 3;
            const int s  = (c & 7) ^ (r & 7);
            const short* ga = A + (size_t)(row0 + r) * K + (k0 + s * 8);
            __builtin_amdgcn_global_load_lds(
                (const __attribute__((address_space(1))) void*)ga,
                (__attribute__((address_space(3))) void*)&As[c0 * 8], 16, 0, 0);
        }
        #pragma unroll
        for (int j = 0; j < 8; ++j) {
            const int c0 = (w * 8 + j) * 64;
            const int c  = c0 + ln;
            const int r  = c >> 3;
            const int s  = (c & 7) ^ (r & 7);
            const short* gb = Bt + (size_t)r * K + (k0 + s * 8);
            __builtin_amdgcn_global_load_lds(
                (const __attribute__((address_space(1))) void*)gb,
                (__attribute__((address_space(3))) void*)&Bs[c0 * 8], 16, 0, 0);
        }
        __syncthreads();

        #pragma unroll
        for (int ks = 0; ks < 2; ++ks) {
            const int slot = ((ks * 4 + lkg) ^ (lrow & 7)) * 8;
            bf16x8 af[4], bfr[4];
            #pragma unroll
            for (int m = 0; m < 4; ++m)
                af[m] = *(const bf16x8*)&As[(m * 16 + lrow) * 64 + slot];
            #pragma unroll
            for (int n = 0; n < 4; ++n)
                bfr[n] = *(const bf16x8*)&Bs[(w * 64 + n * 16 + lrow) * 64 + slot];
            #pragma unroll
            for (int m = 0; m < 4; ++m)
                #pragma unroll
                for (int n = 0; n < 4; ++n)
                    acc[m][n] = __builtin_amdgcn_mfma_f32_16x16x32_bf16(
                        af[m], bfr[n], acc[m][n], 0, 0, 0);
        }
        __syncthreads();
    }

    const int orow = (ln >> 4) * 4;
    const int ocol = ln & 15;

    // add bias into acc
    #pragma unroll
    for (int n = 0; n < 4; ++n) {
        const float bv = bias[w * 64 + n * 16 + ocol];
        #pragma unroll
        for (int m = 0; m < 4; ++m)
            #pragma unroll
            for (int rr = 0; rr < 4; ++rr)
                acc[m][n][rr] += bv;
    }

    // per-row partial (this wave's 64 cols): shuffle-reduce over the 16 lanes
    #pragma unroll
    for (int m = 0; m < 4; ++m) {
        #pragma unroll
        for (int rr = 0; rr < 4; ++rr) {
            float s = 0.f, sq = 0.f;
            #pragma unroll
            for (int n = 0; n < 4; ++n) {
                const float v = acc[m][n][rr];
                s += v; sq += v * v;
            }
            #pragma unroll
            for (int o = 1; o < 16; o <<= 1) {
                s  += __shfl_xor(s, o, 64);
                sq += __shfl_xor(sq, o, 64);
            }
            if (ocol == 0) {
                const int row = m * 16 + orow + rr;
                red[row][w][0] = s;
                red[row][w][1] = sq;
            }
        }
    }
    __syncthreads();

    // finalize LN + residual, write f32 out
    #pragma unroll
    for (int m = 0; m < 4; ++m) {
        #pragma unroll
        for (int rr = 0; rr < 4; ++rr) {
            const int row = m * 16 + orow + rr;
            float S  = red[row][0][0] + red[row][1][0] + red[row][2][0] + red[row][3][0];
            float SQ = red[row][0][1] + red[row][1][1] + red[row][2][1] + red[row][3][1];
            const float mean = S * (1.0f / 256.0f);
            const float var  = SQ * (1.0f / 256.0f) - mean * mean;
            const float rs   = rsqrtf(var + 1e-5f);
            const size_t rbase = (size_t)(row0 + row) * 256;
            #pragma unroll
            for (int n = 0; n < 4; ++n) {
                const int col = w * 64 + n * 16 + ocol;
                const float o = bf2f(xres[rbase + col])
                              + (acc[m][n][rr] - mean) * rs * gamma[col] + beta[col];
                out[rbase + col] = o;
            }
        }
    }
}

// ---------------------------------------------------------------------------
// MSDA sampler, two-phase (unchanged from round 3).
// ---------------------------------------------------------------------------
__global__ __launch_bounds__(256) void msda_sample(
        const float* __restrict__ pm, const short* __restrict__ vcomp,
        short* __restrict__ msda) {
    __shared__ int   s_off[8][32][4];
    __shared__ float s_c[8][32][4];

    const int t  = threadIdx.x;
    const int r0 = blockIdx.x * 8;
    const int bq = r0 >> 14;

    {
        const int g = t >> 5, cmb = t & 31, h = cmb >> 2, p = cmb & 3;
        const int r = r0 + g;
        const int n = r & (NQ_ - 1);
        const int gi = n >> 7, gj = n & 127;
        const float* pr = pm + (size_t)r * 128;

        const float l0 = pr[64 + h * 4 + 0], l1 = pr[64 + h * 4 + 1];
        const float l2 = pr[64 + h * 4 + 2], l3 = pr[64 + h * 4 + 3];
        const float mx = fmaxf(fmaxf(l0, l1), fmaxf(l2, l3));
        const float sum = expf(l0 - mx) + expf(l1 - mx) + expf(l2 - mx) + expf(l3 - mx);
        const float lp = pr[64 + h * 4 + p];
        const float aw = expf(lp - mx) / sum;

        const float ox = pr[h * 8 + p * 2 + 0];
        const float oy = pr[h * 8 + p * 2 + 1];
        const float px = (gj * (1.0f / 127.0f) + ox * (1.0f / 128.0f)) * 128.0f - 0.5f;
        const float py = (gi * (1.0f / 127.0f) + oy * (1.0f / 128.0f)) * 128.0f - 0.5f;
        const float x0f = floorf(px), y0f = floorf(py);
        const int   x0 = (int)x0f, y0 = (int)y0f;
        const float fx = px - x0f, fy = py - y0f;
        const int x0c = min(max(x0, 0), 127), x1c = min(max(x0 + 1, 0), 127);
        const int y0c = min(max(y0, 0), 127), y1c = min(max(y0 + 1, 0), 127);
        const float vx0 = ((unsigned)x0 <= 127u) ? 1.f : 0.f;
        const float vx1 = ((unsigned)(x0 + 1) <= 127u) ? 1.f : 0.f;
        const float vy0 = ((unsigned)y0 <= 127u) ? 1.f : 0.f;
        const float vy1 = ((unsigned)(y0 + 1) <= 127u) ? 1.f : 0.f;

        s_off[g][cmb][0] = (y0c * 128 + x0c) * 512;
        s_off[g][cmb][1] = (y0c * 128 + x1c) * 512;
        s_off[g][cmb][2] = (y1c * 128 + x0c) * 512;
        s_off[g][cmb][3] = (y1c * 128 + x1c) * 512;
        s_c[g][cmb][0] = aw * (1.f - fx) * (1.f - fy) * vx0 * vy0;
        s_c[g][cmb][1] = aw * fx * (1.f - fy) * vx1 * vy0;
        s_c[g][cmb][2] = aw * (1.f - fx) * fy * vx0 * vy1;
        s_c[g][cmb][3] = aw * fx * fy * vx1 * vy1;
    }
    __syncthreads();

    const int half = t >> 7;
    const int h    = (t >> 4) & 7;
    const int dd   = t & 15;
    const char* vb = (const char*)vcomp + ((size_t)bq * NQ_ * 256 + h * 32 + dd * 2) * 2;

    #pragma unroll
    for (int it = 0; it < 4; ++it) {
        const int g = it * 2 + half;
        float a0 = 0.f, a1 = 0.f;
        #pragma unroll
        for (int p = 0; p < 4; ++p) {
            const int cmb = h * 4 + p;
            #pragma unroll
            for (int k = 0; k < 4; ++k) {
                const unsigned u = *(const unsigned*)(vb + s_off[g][cmb][k]);
                const float c = s_c[g][cmb][k];
                a0 += c * __uint_as_float(u << 16);
                a1 += c * __uint_as_float(u & 0xffff0000u);
            }
        }
        const int r = r0 + g;
        const unsigned o = (unsigned)(unsigned short)f2bf(a0)
                         | ((unsigned)(unsigned short)f2bf(a1) << 16);
        *(unsigned*)&msda[(size_t)r * 256 + h * 32 + dd * 2] = o;
    }
}

// ---------------------------------------------------------------------------
extern "C" void kernel_launch(void* const* d_in, const int* in_sizes, int n_in,
                              void* d_out, int out_size, void* d_ws, size_t ws_size,
                              hipStream_t stream) {
    const float* q      = (const float*)d_in[0];
    const float* b_out  = (const float*)d_in[8];
    const float* b1     = (const float*)d_in[10];
    const float* b2     = (const float*)d_in[12];
    const float* gamma  = (const float*)d_in[13];
    const float* beta   = (const float*)d_in[14];

    float* out = (float*)d_out;

    char* w = (char*)d_ws;
    float* pm    = (float*)w; w += (size_t)RTOT_ * 128 * 4;      // 16.8 MB
    short* vcomp = (short*)w; w += (size_t)RTOT_ * 256 * 2;      // 16.8 MB
    short* qbf   = (short*)w; w += (size_t)RTOT_ * EMBED_ * 2;   // 16.8 MB
    short* msda  = (short*)w; w += (size_t)RTOT_ * EMBED_ * 2;   // 16.8 MB
    short* xbf   = (short*)w; w += (size_t)RTOT_ * EMBED_ * 2;   // 16.8 MB
    short* hid   = (short*)w; w += (size_t)RTOT_ * FFN_ * 2;     // 33.6 MB
    short* WcatT = (short*)w; w += WCAT_ELEMS * 2;
    short* WoutT = (short*)w; w += WOUT_ELEMS * 2;
    short* W1T   = (short*)w; w += W1_ELEMS * 2;
    short* W2T   = (short*)w; w += W2_ELEMS * 2;
    float* bcat  = (float*)w; w += NCATP_ * 4;

    prep_weights<<<(PREP_TOTAL + 255) / 256, 256, 0, stream>>>(
        (const float*)d_in[5], (const float*)d_in[1], (const float*)d_in[3],
        (const float*)d_in[6], (const float*)d_in[2], (const float*)d_in[4],
        (const float*)d_in[7], (const float*)d_in[9], (const float*)d_in[11],
        WcatT, WoutT, W1T, W2T, bcat);

    // q -> bf16
    cvt_bf16<<<(RTOT_ * EMBED_ / 8 + 255) / 256, 256, 0, stream>>>(q, qbf);

    // proj: vcomp (bf16 value) + pm (f32 meta)   (32768 x 384 x 256)
    gemm_mfma<EP_SPLIT><<<dim3(NCATP_ / 128, RTOT_ / 128), 256, 0, stream>>>(
        qbf, WcatT, bcat, nullptr, pm, vcomp, RTOT_, NCATP_, EMBED_);

    // MSDA sampling -> msda (bf16)
    msda_sample<<<RTOT_ / 8, 256, 0, stream>>>(pm, vcomp, msda);

    // xbf = bf16(msda @ W_out + b_out + 2q)   (32768 x 256 x 256)
    gemm_mfma<EP_ADD2Q_BF16><<<dim3(EMBED_ / 128, RTOT_ / 128), 256, 0, stream>>>(
        msda, WoutT, b_out, qbf, nullptr, xbf, RTOT_, EMBED_, EMBED_);

    // hid = relu(x @ W1 + b1)                 (32768 x 512 x 256)
    gemm_mfma<EP_RELU_BF16><<<dim3(FFN_ / 128, RTOT_ / 128), 256, 0, stream>>>(
        xbf, W1T, b1, nullptr, nullptr, hid, RTOT_, FFN_, EMBED_);

    // out = x + LN(hid @ W2 + b2)*gamma + beta (32768 x 256 x 512, fused)
    gemm_ln<<<RTOT_ / 64, 256, 0, stream>>>(
        hid, W2T, b2, xbf, gamma, beta, out, RTOT_, FFN_);
}

// Round 5
// 106.687 us; speedup vs baseline: 4.9858x; 1.0072x over previous
//
#include <hip/hip_runtime.h>
#include <hip/hip_bf16.h>
#include <cstddef>
#include <cstdint>

#define B_      2
#define QD_     128
#define NQ_     (QD_ * QD_)          // 16384
#define EMBED_  256
#define HEADS_  8
#define POINTS_ 4
#define FFN_    512
#define RTOT_   (B_ * NQ_)           // 32768
#define NCATP_  384                  // 352 real cols padded to 384

using bf16x8 = __attribute__((ext_vector_type(8))) short;   // 8 bf16 = 4 VGPRs
using f32x4  = __attribute__((ext_vector_type(4))) float;   // MFMA accumulator

__device__ __forceinline__ short f2bf(float f) {
    unsigned u = __float_as_uint(f);
    u += 0x7FFFu + ((u >> 16) & 1u);          // round-to-nearest-even
    return (short)(u >> 16);
}
__device__ __forceinline__ float bf2f(short s) {
    return __uint_as_float(((unsigned)(unsigned short)s) << 16);
}

#define WCAT_ELEMS  (NCATP_ * 256)
#define WOUT_ELEMS  (256 * 256)
#define W1_ELEMS    (512 * 256)
#define W2_ELEMS    (256 * 512)
#define PREP_TOTAL  (WCAT_ELEMS + WOUT_ELEMS + W1_ELEMS + W2_ELEMS)   // 425984
#define CVT_BLOCKS  (RTOT_ * EMBED_ / 8 / 256)                         // 4096
#define PREP_BLOCKS ((PREP_TOTAL + 255) / 256)                         // 1664

// ---------------------------------------------------------------------------
// Fused prep: q->bf16 (blocks [0,4096)) + weight transpose/concat (rest).
// ---------------------------------------------------------------------------
__global__ __launch_bounds__(256) void prep_all(
        const float* __restrict__ q, short* __restrict__ qbf,
        const float* __restrict__ Wv, const float* __restrict__ Wo,
        const float* __restrict__ Wa, const float* __restrict__ bv,
        const float* __restrict__ bo, const float* __restrict__ ba,
        const float* __restrict__ W_out, const float* __restrict__ W1,
        const float* __restrict__ W2,
        short* __restrict__ WcatT, short* __restrict__ WoutT,
        short* __restrict__ W1T, short* __restrict__ W2T,
        float* __restrict__ bcat) {
    const int b = blockIdx.x;
    if (b < CVT_BLOCKS) {
        const size_t i = (size_t)b * 256 + threadIdx.x;
        const float4 f0 = *(const float4*)(q + i * 8);
        const float4 f1 = *(const float4*)(q + i * 8 + 4);
        bf16x8 v;
        v[0] = f2bf(f0.x); v[1] = f2bf(f0.y); v[2] = f2bf(f0.z); v[3] = f2bf(f0.w);
        v[4] = f2bf(f1.x); v[5] = f2bf(f1.y); v[6] = f2bf(f1.z); v[7] = f2bf(f1.w);
        *(bf16x8*)(qbf + i * 8) = v;
        return;
    }
    int idx = (b - CVT_BLOCKS) * 256 + threadIdx.x;
    if (idx < WCAT_ELEMS) {
        int c = idx >> 8, k = idx & 255;
        float v = 0.f;
        if (c < 256)      v = Wv[k * 256 + c];
        else if (c < 320) v = Wo[k * 64 + (c - 256)];
        else if (c < 352) v = Wa[k * 32 + (c - 320)];
        WcatT[idx] = f2bf(v);
    } else if (idx < WCAT_ELEMS + WOUT_ELEMS) {
        int j = idx - WCAT_ELEMS; int c = j >> 8, k = j & 255;
        WoutT[j] = f2bf(W_out[k * 256 + c]);
    } else if (idx < WCAT_ELEMS + WOUT_ELEMS + W1_ELEMS) {
        int j = idx - (WCAT_ELEMS + WOUT_ELEMS); int c = j >> 8, k = j & 255;
        W1T[j] = f2bf(W1[k * 512 + c]);
    } else if (idx < PREP_TOTAL) {
        int j = idx - (WCAT_ELEMS + WOUT_ELEMS + W1_ELEMS); int c = j >> 9, k = j & 511;
        W2T[j] = f2bf(W2[k * 256 + c]);
    }
    if (idx < NCATP_) {
        float v = 0.f;
        if (idx < 256)      v = bv[idx];
        else if (idx < 320) v = bo[idx - 256];
        else if (idx < 352) v = ba[idx - 320];
        bcat[idx] = v;
    }
}

// ---------------------------------------------------------------------------
// bf16 MFMA GEMM, 2-phase double-buffered.
// BM=BN=128, BK=64, 4 waves (2x2), 64x64/wave, 16x16x32 MFMA.
// Per K-step: STAGE(next tile) -> compute(cur) -> one __syncthreads
// (its vmcnt(0) drain lands AFTER the MFMA phase -> latency hidden).
// global_load_lds w16, pre-swizzled source + linear dest, XOR-swizzled reads.
// ---------------------------------------------------------------------------
enum { EP_RELU_BF16 = 1, EP_ADD2Q_BF16 = 2, EP_SPLIT = 3 };

template <int EP>
__global__ __launch_bounds__(256) void gemm_mfma(
        const short* __restrict__ A,            // [M][K] bf16
        const short* __restrict__ Bt,           // [N][K] bf16
        const float* __restrict__ bias,         // [N]
        const short* __restrict__ extra,        // qbf (ADD2Q) else nullptr
        float* __restrict__ Cf,                 // pm (SPLIT) else nullptr
        short* __restrict__ Cb,                 // bf16 out
        int M, int N, int K) {
    __shared__ __align__(16) short As[2][128 * 64];   // 16 KB x2
    __shared__ __align__(16) short Bs[2][128 * 64];   // 16 KB x2

    const int t    = threadIdx.x;
    const int ln   = t & 63;
    const int w    = t >> 6;
    const int wr   = w >> 1;
    const int wc   = w & 1;
    const int lrow = ln & 15;
    const int lkg  = ln >> 4;

    // XCD-aware bijective swizzle (nwg % 8 == 0 for all our grids)
    const int gx   = gridDim.x;
    const int nwg  = gx * gridDim.y;
    const int flat = blockIdx.y * gx + blockIdx.x;
    const int q8   = nwg >> 3;
    const int swz  = (flat & 7) * q8 + (flat >> 3);
    const int row0 = (swz / gx) * 128;
    const int col0 = (swz % gx) * 128;

    f32x4 acc[4][4] = {};

    auto stage = [&](int buf, int k0) {
        #pragma unroll
        for (int j = 0; j < 4; ++j) {
            const int c0 = (w * 4 + j) * 64;        // wave-uniform chunk base
            const int c  = c0 + ln;
            const int r  = c >> 3;
            const int s  = (c & 7) ^ (r & 7);       // pre-swizzled source chunk
            const short* ga = A  + (size_t)(row0 + r) * K + (k0 + s * 8);
            const short* gb = Bt + (size_t)(col0 + r) * K + (k0 + s * 8);
            __builtin_amdgcn_global_load_lds(
                (const __attribute__((address_space(1))) void*)ga,
                (__attribute__((address_space(3))) void*)&As[buf][c0 * 8], 16, 0, 0);
            __builtin_amdgcn_global_load_lds(
                (const __attribute__((address_space(1))) void*)gb,
                (__attribute__((address_space(3))) void*)&Bs[buf][c0 * 8], 16, 0, 0);
        }
    };

    stage(0, 0);
    __syncthreads();
    int cur = 0;
    for (int k0 = 0; k0 < K; k0 += 64) {
        if (k0 + 64 < K) stage(cur ^ 1, k0 + 64);   // prefetch next tile
        #pragma unroll
        for (int ks = 0; ks < 2; ++ks) {
            const int slot = ((ks * 4 + lkg) ^ (lrow & 7)) * 8;
            bf16x8 af[4], bfr[4];
            #pragma unroll
            for (int m = 0; m < 4; ++m)
                af[m] = *(const bf16x8*)&As[cur][(wr * 64 + m * 16 + lrow) * 64 + slot];
            #pragma unroll
            for (int n = 0; n < 4; ++n)
                bfr[n] = *(const bf16x8*)&Bs[cur][(wc * 64 + n * 16 + lrow) * 64 + slot];
            #pragma unroll
            for (int m = 0; m < 4; ++m)
                #pragma unroll
                for (int n = 0; n < 4; ++n)
                    acc[m][n] = __builtin_amdgcn_mfma_f32_16x16x32_bf16(
                        af[m], bfr[n], acc[m][n], 0, 0, 0);
        }
        __syncthreads();            // drains vmcnt(0): next tile landed
        cur ^= 1;
    }

    // C/D mapping: col = ln&15, row = (ln>>4)*4 + reg
    const int orow = (ln >> 4) * 4;
    const int ocol = ln & 15;
    #pragma unroll
    for (int m = 0; m < 4; ++m) {
        #pragma unroll
        for (int n = 0; n < 4; ++n) {
            const int col = col0 + wc * 64 + n * 16 + ocol;
            const float bv = bias[col];
            #pragma unroll
            for (int rr = 0; rr < 4; ++rr) {
                const int row = row0 + wr * 64 + m * 16 + orow + rr;
                float v = acc[m][n][rr] + bv;
                if (EP == EP_SPLIT) {
                    if (col < 256) Cb[(size_t)row * 256 + col] = f2bf(v);
                    else           Cf[(size_t)row * 128 + (col - 256)] = v;
                } else if (EP == EP_RELU_BF16) {
                    Cb[(size_t)row * N + col] = f2bf(fmaxf(v, 0.f));
                } else if (EP == EP_ADD2Q_BF16) {
                    v += 2.f * bf2f(extra[(size_t)row * N + col]);
                    Cb[(size_t)row * N + col] = f2bf(v);
                }
            }
        }
    }
}

// ---------------------------------------------------------------------------
// Fused W2 GEMM + LayerNorm + residual:  out = x + LN(hid@W2 + b2)*g + beta
// BM=128, BN=256 (full rows), BK=64, 8 waves (2x4), 64x64/wave, dbuf 2-phase.
// LN stats from f32 accumulators: 16-lane shuffle + LDS cross-wave combine.
// ---------------------------------------------------------------------------
__global__ __launch_bounds__(512) void gemm_ln(
        const short* __restrict__ A,            // hid [M][512] bf16
        const short* __restrict__ Bt,           // W2T [256][512] bf16
        const float* __restrict__ bias,         // b2
        const short* __restrict__ xres,         // xbf [M][256] bf16
        const float* __restrict__ gamma, const float* __restrict__ beta,
        float* __restrict__ out, int M, int K) {
    __shared__ __align__(16) short As[2][128 * 64];   // 16 KB x2
    __shared__ __align__(16) short Bs[2][256 * 64];   // 32 KB x2
    __shared__ float red[128][4][2];                  // 4 KB

    const int t    = threadIdx.x;
    const int ln   = t & 63;
    const int w    = t >> 6;            // 0..7
    const int wr   = w >> 2;            // 0..1 (row half)
    const int wc   = w & 3;             // 0..3 (col quarter)
    const int lrow = ln & 15;
    const int lkg  = ln >> 4;
    const int row0 = blockIdx.x * 128;

    f32x4 acc[4][4] = {};

    auto stage = [&](int buf, int k0) {
        #pragma unroll
        for (int j = 0; j < 2; ++j) {               // A: 1024 chunks / 512 thr
            const int c0 = (w * 2 + j) * 64;
            const int c  = c0 + ln;
            const int r  = c >> 3;
            const int s  = (c & 7) ^ (r & 7);
            const short* ga = A + (size_t)(row0 + r) * K + (k0 + s * 8);
            __builtin_amdgcn_global_load_lds(
                (const __attribute__((address_space(1))) void*)ga,
                (__attribute__((address_space(3))) void*)&As[buf][c0 * 8], 16, 0, 0);
        }
        #pragma unroll
        for (int j = 0; j < 4; ++j) {               // B: 2048 chunks / 512 thr
            const int c0 = (w * 4 + j) * 64;
            const int c  = c0 + ln;
            const int r  = c >> 3;
            const int s  = (c & 7) ^ (r & 7);
            const short* gb = Bt + (size_t)r * K + (k0 + s * 8);
            __builtin_amdgcn_global_load_lds(
                (const __attribute__((address_space(1))) void*)gb,
                (__attribute__((address_space(3))) void*)&Bs[buf][c0 * 8], 16, 0, 0);
        }
    };

    stage(0, 0);
    __syncthreads();
    int cur = 0;
    for (int k0 = 0; k0 < K; k0 += 64) {
        if (k0 + 64 < K) stage(cur ^ 1, k0 + 64);
        #pragma unroll
        for (int ks = 0; ks < 2; ++ks) {
            const int slot = ((ks * 4 + lkg) ^ (lrow & 7)) * 8;
            bf16x8 af[4], bfr[4];
            #pragma unroll
            for (int m = 0; m < 4; ++m)
                af[m] = *(const bf16x8*)&As[cur][(wr * 64 + m * 16 + lrow) * 64 + slot];
            #pragma unroll
            for (int n = 0; n < 4; ++n)
                bfr[n] = *(const bf16x8*)&Bs[cur][(wc * 64 + n * 16 + lrow) * 64 + slot];
            #pragma unroll
            for (int m = 0; m < 4; ++m)
                #pragma unroll
                for (int n = 0; n < 4; ++n)
                    acc[m][n] = __builtin_amdgcn_mfma_f32_16x16x32_bf16(
                        af[m], bfr[n], acc[m][n], 0, 0, 0);
        }
        __syncthreads();
        cur ^= 1;
    }

    const int orow = (ln >> 4) * 4;
    const int ocol = ln & 15;

    // bias into acc
    #pragma unroll
    for (int n = 0; n < 4; ++n) {
        const float bv = bias[wc * 64 + n * 16 + ocol];
        #pragma unroll
        for (int m = 0; m < 4; ++m)
            #pragma unroll
            for (int rr = 0; rr < 4; ++rr)
                acc[m][n][rr] += bv;
    }

    // per-row partials over this wave's 64 cols (16-lane shuffle reduce)
    #pragma unroll
    for (int m = 0; m < 4; ++m) {
        #pragma unroll
        for (int rr = 0; rr < 4; ++rr) {
            float s = 0.f, sq = 0.f;
            #pragma unroll
            for (int n = 0; n < 4; ++n) {
                const float v = acc[m][n][rr];
                s += v; sq += v * v;
            }
            #pragma unroll
            for (int o = 1; o < 16; o <<= 1) {
                s  += __shfl_xor(s, o, 64);
                sq += __shfl_xor(sq, o, 64);
            }
            if (ocol == 0) {
                const int row = wr * 64 + m * 16 + orow + rr;
                red[row][wc][0] = s;
                red[row][wc][1] = sq;
            }
        }
    }
    __syncthreads();

    // finalize LN + residual, write f32 out
    #pragma unroll
    for (int m = 0; m < 4; ++m) {
        #pragma unroll
        for (int rr = 0; rr < 4; ++rr) {
            const int row = wr * 64 + m * 16 + orow + rr;
            const float S  = red[row][0][0] + red[row][1][0] + red[row][2][0] + red[row][3][0];
            const float SQ = red[row][0][1] + red[row][1][1] + red[row][2][1] + red[row][3][1];
            const float mean = S * (1.0f / 256.0f);
            const float var  = SQ * (1.0f / 256.0f) - mean * mean;
            const float rs   = rsqrtf(var + 1e-5f);
            const size_t rbase = (size_t)(row0 + row) * 256;
            #pragma unroll
            for (int n = 0; n < 4; ++n) {
                const int col = wc * 64 + n * 16 + ocol;
                out[rbase + col] = bf2f(xres[rbase + col])
                                 + (acc[m][n][rr] - mean) * rs * gamma[col] + beta[col];
            }
        }
    }
}

// ---------------------------------------------------------------------------
// MSDA sampler, two-phase (unchanged).
// ---------------------------------------------------------------------------
__global__ __launch_bounds__(256) void msda_sample(
        const float* __restrict__ pm, const short* __restrict__ vcomp,
        short* __restrict__ msda) {
    __shared__ int   s_off[8][32][4];
    __shared__ float s_c[8][32][4];

    const int t  = threadIdx.x;
    const int r0 = blockIdx.x * 8;
    const int bq = r0 >> 14;

    {
        const int g = t >> 5, cmb = t & 31, h = cmb >> 2, p = cmb & 3;
        const int r = r0 + g;
        const int n = r & (NQ_ - 1);
        const int gi = n >> 7, gj = n & 127;
        const float* pr = pm + (size_t)r * 128;

        const float l0 = pr[64 + h * 4 + 0], l1 = pr[64 + h * 4 + 1];
        const float l2 = pr[64 + h * 4 + 2], l3 = pr[64 + h * 4 + 3];
        const float mx = fmaxf(fmaxf(l0, l1), fmaxf(l2, l3));
        const float sum = expf(l0 - mx) + expf(l1 - mx) + expf(l2 - mx) + expf(l3 - mx);
        const float lp = pr[64 + h * 4 + p];
        const float aw = expf(lp - mx) / sum;

        const float ox = pr[h * 8 + p * 2 + 0];
        const float oy = pr[h * 8 + p * 2 + 1];
        const float px = (gj * (1.0f / 127.0f) + ox * (1.0f / 128.0f)) * 128.0f - 0.5f;
        const float py = (gi * (1.0f / 127.0f) + oy * (1.0f / 128.0f)) * 128.0f - 0.5f;
        const float x0f = floorf(px), y0f = floorf(py);
        const int   x0 = (int)x0f, y0 = (int)y0f;
        const float fx = px - x0f, fy = py - y0f;
        const int x0c = min(max(x0, 0), 127), x1c = min(max(x0 + 1, 0), 127);
        const int y0c = min(max(y0, 0), 127), y1c = min(max(y0 + 1, 0), 127);
        const float vx0 = ((unsigned)x0 <= 127u) ? 1.f : 0.f;
        const float vx1 = ((unsigned)(x0 + 1) <= 127u) ? 1.f : 0.f;
        const float vy0 = ((unsigned)y0 <= 127u) ? 1.f : 0.f;
        const float vy1 = ((unsigned)(y0 + 1) <= 127u) ? 1.f : 0.f;

        s_off[g][cmb][0] = (y0c * 128 + x0c) * 512;
        s_off[g][cmb][1] = (y0c * 128 + x1c) * 512;
        s_off[g][cmb][2] = (y1c * 128 + x0c) * 512;
        s_off[g][cmb][3] = (y1c * 128 + x1c) * 512;
        s_c[g][cmb][0] = aw * (1.f - fx) * (1.f - fy) * vx0 * vy0;
        s_c[g][cmb][1] = aw * fx * (1.f - fy) * vx1 * vy0;
        s_c[g][cmb][2] = aw * (1.f - fx) * fy * vx0 * vy1;
        s_c[g][cmb][3] = aw * fx * fy * vx1 * vy1;
    }
    __syncthreads();

    const int half = t >> 7;
    const int h    = (t >> 4) & 7;
    const int dd   = t & 15;
    const char* vb = (const char*)vcomp + ((size_t)bq * NQ_ * 256 + h * 32 + dd * 2) * 2;

    #pragma unroll
    for (int it = 0; it < 4; ++it) {
        const int g = it * 2 + half;
        float a0 = 0.f, a1 = 0.f;
        #pragma unroll
        for (int p = 0; p < 4; ++p) {
            const int cmb = h * 4 + p;
            #pragma unroll
            for (int k = 0; k < 4; ++k) {
                const unsigned u = *(const unsigned*)(vb + s_off[g][cmb][k]);
                const float c = s_c[g][cmb][k];
                a0 += c * __uint_as_float(u << 16);
                a1 += c * __uint_as_float(u & 0xffff0000u);
            }
        }
        const int r = r0 + g;
        const unsigned o = (unsigned)(unsigned short)f2bf(a0)
                         | ((unsigned)(unsigned short)f2bf(a1) << 16);
        *(unsigned*)&msda[(size_t)r * 256 + h * 32 + dd * 2] = o;
    }
}

// ---------------------------------------------------------------------------
extern "C" void kernel_launch(void* const* d_in, const int* in_sizes, int n_in,
                              void* d_out, int out_size, void* d_ws, size_t ws_size,
                              hipStream_t stream) {
    const float* q      = (const float*)d_in[0];
    const float* b_out  = (const float*)d_in[8];
    const float* b1     = (const float*)d_in[10];
    const float* b2     = (const float*)d_in[12];
    const float* gamma  = (const float*)d_in[13];
    const float* beta   = (const float*)d_in[14];

    float* out = (float*)d_out;

    char* w = (char*)d_ws;
    float* pm    = (float*)w; w += (size_t)RTOT_ * 128 * 4;      // 16.8 MB
    short* vcomp = (short*)w; w += (size_t)RTOT_ * 256 * 2;      // 16.8 MB
    short* qbf   = (short*)w; w += (size_t)RTOT_ * EMBED_ * 2;   // 16.8 MB
    short* msda  = (short*)w; w += (size_t)RTOT_ * EMBED_ * 2;   // 16.8 MB
    short* xbf   = (short*)w; w += (size_t)RTOT_ * EMBED_ * 2;   // 16.8 MB
    short* hid   = (short*)w; w += (size_t)RTOT_ * FFN_ * 2;     // 33.6 MB
    short* WcatT = (short*)w; w += WCAT_ELEMS * 2;
    short* WoutT = (short*)w; w += WOUT_ELEMS * 2;
    short* W1T   = (short*)w; w += W1_ELEMS * 2;
    short* W2T   = (short*)w; w += W2_ELEMS * 2;
    float* bcat  = (float*)w; w += NCATP_ * 4;

    // q->bf16 + weight prep (one launch)
    prep_all<<<CVT_BLOCKS + PREP_BLOCKS, 256, 0, stream>>>(
        q, qbf,
        (const float*)d_in[5], (const float*)d_in[1], (const float*)d_in[3],
        (const float*)d_in[6], (const float*)d_in[2], (const float*)d_in[4],
        (const float*)d_in[7], (const float*)d_in[9], (const float*)d_in[11],
        WcatT, WoutT, W1T, W2T, bcat);

    // proj: vcomp (bf16 value) + pm (f32 meta)   (32768 x 384 x 256)
    gemm_mfma<EP_SPLIT><<<dim3(NCATP_ / 128, RTOT_ / 128), 256, 0, stream>>>(
        qbf, WcatT, bcat, nullptr, pm, vcomp, RTOT_, NCATP_, EMBED_);

    // MSDA sampling -> msda (bf16)
    msda_sample<<<RTOT_ / 8, 256, 0, stream>>>(pm, vcomp, msda);

    // xbf = bf16(msda @ W_out + b_out + 2q)   (32768 x 256 x 256)
    gemm_mfma<EP_ADD2Q_BF16><<<dim3(EMBED_ / 128, RTOT_ / 128), 256, 0, stream>>>(
        msda, WoutT, b_out, qbf, nullptr, xbf, RTOT_, EMBED_, EMBED_);

    // hid = relu(x @ W1 + b1)                 (32768 x 512 x 256)
    gemm_mfma<EP_RELU_BF16><<<dim3(FFN_ / 128, RTOT_ / 128), 256, 0, stream>>>(
        xbf, W1T, b1, nullptr, nullptr, hid, RTOT_, FFN_, EMBED_);

    // out = x + LN(hid @ W2 + b2)*gamma + beta (32768 x 256 x 512, fused)
    gemm_ln<<<RTOT_ / 128, 512, 0, stream>>>(
        hid, W2T, b2, xbf, gamma, beta, out, RTOT_, FFN_);
}

// Round 6
// 104.631 us; speedup vs baseline: 5.0837x; 1.0197x over previous
//
#include <hip/hip_runtime.h>
#include <hip/hip_bf16.h>
#include <cstddef>
#include <cstdint>

#define B_      2
#define QD_     128
#define NQ_     (QD_ * QD_)          // 16384
#define EMBED_  256
#define HEADS_  8
#define POINTS_ 4
#define FFN_    512
#define RTOT_   (B_ * NQ_)           // 32768
#define NCATP_  384                  // 352 real cols padded to 384

using bf16x8 = __attribute__((ext_vector_type(8))) short;   // 8 bf16 = 4 VGPRs
using f32x4  = __attribute__((ext_vector_type(4))) float;   // MFMA accumulator

__device__ __forceinline__ short f2bf(float f) {
    unsigned u = __float_as_uint(f);
    u += 0x7FFFu + ((u >> 16) & 1u);          // round-to-nearest-even
    return (short)(u >> 16);
}
__device__ __forceinline__ float bf2f(short s) {
    return __uint_as_float(((unsigned)(unsigned short)s) << 16);
}

#define GLDS(gp, lp) __builtin_amdgcn_global_load_lds( \
        (const __attribute__((address_space(1))) void*)(gp), \
        (__attribute__((address_space(3))) void*)(lp), 16, 0, 0)

#define WCAT_ELEMS  (NCATP_ * 256)
#define WOUT_ELEMS  (256 * 256)
#define W1_ELEMS    (512 * 256)
#define W2_ELEMS    (256 * 512)
#define PREP_TOTAL  (WCAT_ELEMS + WOUT_ELEMS + W1_ELEMS + W2_ELEMS)   // 425984
#define CVT_BLOCKS  (RTOT_ * EMBED_ / 8 / 256)                         // 4096
#define PREP_BLOCKS ((PREP_TOTAL + 255) / 256)                         // 1664

// ---------------------------------------------------------------------------
// Fused prep: q->bf16 (blocks [0,4096)) + weight transpose/concat (rest).
// ---------------------------------------------------------------------------
__global__ __launch_bounds__(256) void prep_all(
        const float* __restrict__ q, short* __restrict__ qbf,
        const float* __restrict__ Wv, const float* __restrict__ Wo,
        const float* __restrict__ Wa, const float* __restrict__ bv,
        const float* __restrict__ bo, const float* __restrict__ ba,
        const float* __restrict__ W_out, const float* __restrict__ W1,
        const float* __restrict__ W2,
        short* __restrict__ WcatT, short* __restrict__ WoutT,
        short* __restrict__ W1T, short* __restrict__ W2T,
        float* __restrict__ bcat) {
    const int b = blockIdx.x;
    if (b < CVT_BLOCKS) {
        const size_t i = (size_t)b * 256 + threadIdx.x;
        const float4 f0 = *(const float4*)(q + i * 8);
        const float4 f1 = *(const float4*)(q + i * 8 + 4);
        bf16x8 v;
        v[0] = f2bf(f0.x); v[1] = f2bf(f0.y); v[2] = f2bf(f0.z); v[3] = f2bf(f0.w);
        v[4] = f2bf(f1.x); v[5] = f2bf(f1.y); v[6] = f2bf(f1.z); v[7] = f2bf(f1.w);
        *(bf16x8*)(qbf + i * 8) = v;
        return;
    }
    int idx = (b - CVT_BLOCKS) * 256 + threadIdx.x;
    if (idx < WCAT_ELEMS) {
        int c = idx >> 8, k = idx & 255;
        float v = 0.f;
        if (c < 256)      v = Wv[k * 256 + c];
        else if (c < 320) v = Wo[k * 64 + (c - 256)];
        else if (c < 352) v = Wa[k * 32 + (c - 320)];
        WcatT[idx] = f2bf(v);
    } else if (idx < WCAT_ELEMS + WOUT_ELEMS) {
        int j = idx - WCAT_ELEMS; int c = j >> 8, k = j & 255;
        WoutT[j] = f2bf(W_out[k * 256 + c]);
    } else if (idx < WCAT_ELEMS + WOUT_ELEMS + W1_ELEMS) {
        int j = idx - (WCAT_ELEMS + WOUT_ELEMS); int c = j >> 8, k = j & 255;
        W1T[j] = f2bf(W1[k * 512 + c]);
    } else if (idx < PREP_TOTAL) {
        int j = idx - (WCAT_ELEMS + WOUT_ELEMS + W1_ELEMS); int c = j >> 9, k = j & 511;
        W2T[j] = f2bf(W2[k * 256 + c]);
    }
    if (idx < NCATP_) {
        float v = 0.f;
        if (idx < 256)      v = bv[idx];
        else if (idx < 320) v = bo[idx - 256];
        else if (idx < 352) v = ba[idx - 320];
        bcat[idx] = v;
    }
}

// ---------------------------------------------------------------------------
// bf16 MFMA GEMM, 2-phase double-buffered (unchanged from round 5).
// BM=BN=128, BK=64, 4 waves (2x2), 64x64/wave, 16x16x32 MFMA.
// ---------------------------------------------------------------------------
enum { EP_ADD2Q_BF16 = 2, EP_SPLIT = 3 };

template <int EP>
__global__ __launch_bounds__(256) void gemm_mfma(
        const short* __restrict__ A,            // [M][K] bf16
        const short* __restrict__ Bt,           // [N][K] bf16
        const float* __restrict__ bias,         // [N]
        const short* __restrict__ extra,        // qbf (ADD2Q) else nullptr
        float* __restrict__ Cf,                 // pm (SPLIT) else nullptr
        short* __restrict__ Cb,                 // bf16 out
        int M, int N, int K) {
    __shared__ __align__(16) short As[2][128 * 64];
    __shared__ __align__(16) short Bs[2][128 * 64];

    const int t    = threadIdx.x;
    const int ln   = t & 63;
    const int w    = t >> 6;
    const int wr   = w >> 1;
    const int wc   = w & 1;
    const int lrow = ln & 15;
    const int lkg  = ln >> 4;

    const int gx   = gridDim.x;
    const int nwg  = gx * gridDim.y;
    const int flat = blockIdx.y * gx + blockIdx.x;
    const int q8   = nwg >> 3;
    const int swz  = (flat & 7) * q8 + (flat >> 3);
    const int row0 = (swz / gx) * 128;
    const int col0 = (swz % gx) * 128;

    f32x4 acc[4][4] = {};

    auto stage = [&](int buf, int k0) {
        #pragma unroll
        for (int j = 0; j < 4; ++j) {
            const int c0 = (w * 4 + j) * 64;
            const int c  = c0 + ln;
            const int r  = c >> 3;
            const int s  = (c & 7) ^ (r & 7);
            GLDS(A  + (size_t)(row0 + r) * K + (k0 + s * 8), &As[buf][c0 * 8]);
            GLDS(Bt + (size_t)(col0 + r) * K + (k0 + s * 8), &Bs[buf][c0 * 8]);
        }
    };

    stage(0, 0);
    __syncthreads();
    int cur = 0;
    for (int k0 = 0; k0 < K; k0 += 64) {
        if (k0 + 64 < K) stage(cur ^ 1, k0 + 64);
        #pragma unroll
        for (int ks = 0; ks < 2; ++ks) {
            const int slot = ((ks * 4 + lkg) ^ (lrow & 7)) * 8;
            bf16x8 af[4], bfr[4];
            #pragma unroll
            for (int m = 0; m < 4; ++m)
                af[m] = *(const bf16x8*)&As[cur][(wr * 64 + m * 16 + lrow) * 64 + slot];
            #pragma unroll
            for (int n = 0; n < 4; ++n)
                bfr[n] = *(const bf16x8*)&Bs[cur][(wc * 64 + n * 16 + lrow) * 64 + slot];
            #pragma unroll
            for (int m = 0; m < 4; ++m)
                #pragma unroll
                for (int n = 0; n < 4; ++n)
                    acc[m][n] = __builtin_amdgcn_mfma_f32_16x16x32_bf16(
                        af[m], bfr[n], acc[m][n], 0, 0, 0);
        }
        __syncthreads();
        cur ^= 1;
    }

    const int orow = (ln >> 4) * 4;
    const int ocol = ln & 15;
    #pragma unroll
    for (int m = 0; m < 4; ++m) {
        #pragma unroll
        for (int n = 0; n < 4; ++n) {
            const int col = col0 + wc * 64 + n * 16 + ocol;
            const float bv = bias[col];
            #pragma unroll
            for (int rr = 0; rr < 4; ++rr) {
                const int row = row0 + wr * 64 + m * 16 + orow + rr;
                float v = acc[m][n][rr] + bv;
                if (EP == EP_SPLIT) {
                    if (col < 256) Cb[(size_t)row * 256 + col] = f2bf(v);
                    else           Cf[(size_t)row * 128 + (col - 256)] = v;
                } else if (EP == EP_ADD2Q_BF16) {
                    v += 2.f * bf2f(extra[(size_t)row * N + col]);
                    Cb[(size_t)row * N + col] = f2bf(v);
                }
            }
        }
    }
}

// ---------------------------------------------------------------------------
// Fused FFN: out = x + LN(relu(x@W1+b1)@W2 + b2)*gamma + beta
// One block = 128 rows, 512 threads (8 waves, 2 row-halves x 4 col-groups).
// x (128x256) staged once in LDS (also serves as residual source).
// 4 hidden chunks of 128: hid = relu(x@W1c+b1) -> bf16 LDS half-tiles ->
// acc2 += hid @ W2c. W1 double-buffered; W2 t0 prefetched under last W1 step.
// ---------------------------------------------------------------------------
__global__ __launch_bounds__(512) void ffn_ln(
        const short* __restrict__ xbf,          // [M][256] bf16
        const short* __restrict__ W1T,          // [512][256] bf16
        const float* __restrict__ b1,           // [512]
        const short* __restrict__ W2T,          // [256][512] bf16
        const float* __restrict__ b2,           // [256]
        const float* __restrict__ gamma, const float* __restrict__ beta,
        float* __restrict__ out) {
    __shared__ __align__(16) short xs[4 * 128 * 64];   // 64 KB: x, 4 k-steps
    __shared__ __align__(16) short hl[128 * 64];       // 16 KB: hid half-tile
    __shared__ __align__(16) short wb[2 * 128 * 64];   // 32 KB: W1 dbuf
    __shared__ __align__(16) short w2b[256 * 64];      // 32 KB: W2 tile
    __shared__ float red[128][4][2];                   // 4 KB

    const int t    = threadIdx.x;
    const int ln   = t & 63;
    const int w    = t >> 6;            // 0..7
    const int wr   = w >> 2;            // 0..1 (row half)
    const int wc   = w & 3;             // 0..3 (col group)
    const int lrow = ln & 15;
    const int lkg  = ln >> 4;
    const int row0 = blockIdx.x * 128;

    auto stage_x = [&]() {
        #pragma unroll
        for (int j = 0; j < 8; ++j) {
            const int c0 = (w * 8 + j) * 64;
            const int cc = c0 + ln;
            const int kt = cc >> 10, rem = cc & 1023;
            const int r = rem >> 3;
            const int s = (rem & 7) ^ (r & 7);
            GLDS(xbf + (size_t)(row0 + r) * 256 + kt * 64 + s * 8, &xs[c0 * 8]);
        }
    };
    auto stage_w1 = [&](int c, int kt, int buf) {
        #pragma unroll
        for (int j = 0; j < 2; ++j) {
            const int c0 = (w * 2 + j) * 64;
            const int cc = c0 + ln;
            const int r = cc >> 3;
            const int s = (cc & 7) ^ (r & 7);
            GLDS(W1T + (size_t)(c * 128 + r) * 256 + kt * 64 + s * 8,
                 &wb[buf * 8192 + c0 * 8]);
        }
    };
    auto stage_w2 = [&](int c, int kt2) {
        #pragma unroll
        for (int j = 0; j < 4; ++j) {
            const int c0 = (w * 4 + j) * 64;
            const int cc = c0 + ln;
            const int r = cc >> 3;
            const int s = (cc & 7) ^ (r & 7);
            GLDS(W2T + (size_t)r * 512 + c * 128 + kt2 * 64 + s * 8,
                 &w2b[c0 * 8]);
        }
    };

    f32x4 acc2[4][4] = {};

    stage_x();
    stage_w1(0, 0, 0);
    __syncthreads();

    #pragma unroll 1
    for (int c = 0; c < 4; ++c) {
        // ---- first GEMM: hid chunk (128 rows x 128 hidden), K=256 ----
        f32x4 acc1[4][2] = {};
        int buf = 0;
        #pragma unroll
        for (int kt = 0; kt < 4; ++kt) {
            if (kt < 3) {
                stage_w1(c, kt + 1, buf ^ 1);
            } else {
                stage_w2(c, 0);
                if (c < 3) stage_w1(c + 1, 0, 0);
            }
            #pragma unroll
            for (int ks = 0; ks < 2; ++ks) {
                const int slot = ((ks * 4 + lkg) ^ (lrow & 7)) * 8;
                bf16x8 af[4], bfr[2];
                #pragma unroll
                for (int m = 0; m < 4; ++m)
                    af[m] = *(const bf16x8*)&xs[kt * 8192 + (wr * 64 + m * 16 + lrow) * 64 + slot];
                #pragma unroll
                for (int n = 0; n < 2; ++n)
                    bfr[n] = *(const bf16x8*)&wb[buf * 8192 + (wc * 32 + n * 16 + lrow) * 64 + slot];
                #pragma unroll
                for (int m = 0; m < 4; ++m)
                    #pragma unroll
                    for (int n = 0; n < 2; ++n)
                        acc1[m][n] = __builtin_amdgcn_mfma_f32_16x16x32_bf16(
                            af[m], bfr[n], acc1[m][n], 0, 0, 0);
            }
            __syncthreads();
            buf ^= 1;
        }

        // ---- two hidden half-tiles: store hid -> LDS, then acc2 += hid@W2 ----
        #pragma unroll
        for (int half = 0; half < 2; ++half) {
            if (half == 1) stage_w2(c, 1);           // w2b free (post-barrier)
            if ((wc >> 1) == half) {                 // this wave's cols in half
                #pragma unroll
                for (int n = 0; n < 2; ++n) {
                    const int kk = (wc & 1) * 32 + n * 16 + lrow;
                    const float bv = b1[c * 128 + half * 64 + kk];
                    #pragma unroll
                    for (int m = 0; m < 4; ++m)
                        #pragma unroll
                        for (int rr = 0; rr < 4; ++rr) {
                            const int row = wr * 64 + m * 16 + lkg * 4 + rr;
                            const float v = fmaxf(acc1[m][n][rr] + bv, 0.f);
                            hl[row * 64 + ((kk >> 3) ^ (row & 7)) * 8 + (kk & 7)] = f2bf(v);
                        }
                }
            }
            __syncthreads();                         // hl + W2 tile ready
            #pragma unroll
            for (int ks = 0; ks < 2; ++ks) {
                const int slot = ((ks * 4 + lkg) ^ (lrow & 7)) * 8;
                bf16x8 af[4], bfr[4];
                #pragma unroll
                for (int m = 0; m < 4; ++m)
                    af[m] = *(const bf16x8*)&hl[(wr * 64 + m * 16 + lrow) * 64 + slot];
                #pragma unroll
                for (int n = 0; n < 4; ++n)
                    bfr[n] = *(const bf16x8*)&w2b[(wc * 64 + n * 16 + lrow) * 64 + slot];
                #pragma unroll
                for (int m = 0; m < 4; ++m)
                    #pragma unroll
                    for (int n = 0; n < 4; ++n)
                        acc2[m][n] = __builtin_amdgcn_mfma_f32_16x16x32_bf16(
                            af[m], bfr[n], acc2[m][n], 0, 0, 0);
            }
            __syncthreads();                         // w2b + hl free
        }
    }

    // ---- epilogue: bias, LN stats, residual from xs, f32 store ----
    const int orow = lkg * 4;
    const int ocol = lrow;
    #pragma unroll
    for (int n = 0; n < 4; ++n) {
        const float bv = b2[wc * 64 + n * 16 + ocol];
        #pragma unroll
        for (int m = 0; m < 4; ++m)
            #pragma unroll
            for (int rr = 0; rr < 4; ++rr)
                acc2[m][n][rr] += bv;
    }

    #pragma unroll
    for (int m = 0; m < 4; ++m) {
        #pragma unroll
        for (int rr = 0; rr < 4; ++rr) {
            float s = 0.f, sq = 0.f;
            #pragma unroll
            for (int n = 0; n < 4; ++n) {
                const float v = acc2[m][n][rr];
                s += v; sq += v * v;
            }
            #pragma unroll
            for (int o = 1; o < 16; o <<= 1) {
                s  += __shfl_xor(s, o, 64);
                sq += __shfl_xor(sq, o, 64);
            }
            if (ocol == 0) {
                const int row = wr * 64 + m * 16 + orow + rr;
                red[row][wc][0] = s;
                red[row][wc][1] = sq;
            }
        }
    }
    __syncthreads();

    #pragma unroll
    for (int m = 0; m < 4; ++m) {
        #pragma unroll
        for (int rr = 0; rr < 4; ++rr) {
            const int row = wr * 64 + m * 16 + orow + rr;
            const float S  = red[row][0][0] + red[row][1][0] + red[row][2][0] + red[row][3][0];
            const float SQ = red[row][0][1] + red[row][1][1] + red[row][2][1] + red[row][3][1];
            const float mean = S * (1.0f / 256.0f);
            const float var  = SQ * (1.0f / 256.0f) - mean * mean;
            const float rs   = rsqrtf(var + 1e-5f);
            const size_t rbase = (size_t)(row0 + row) * 256;
            #pragma unroll
            for (int n = 0; n < 4; ++n) {
                const int col = wc * 64 + n * 16 + ocol;
                const int kk  = n * 16 + ocol;
                const float xv = bf2f(xs[wc * 8192 + row * 64 +
                                         ((kk >> 3) ^ (row & 7)) * 8 + (kk & 7)]);
                out[rbase + col] = xv + (acc2[m][n][rr] - mean) * rs * gamma[col] + beta[col];
            }
        }
    }
}

// ---------------------------------------------------------------------------
// MSDA sampler, two-phase (unchanged).
// ---------------------------------------------------------------------------
__global__ __launch_bounds__(256) void msda_sample(
        const float* __restrict__ pm, const short* __restrict__ vcomp,
        short* __restrict__ msda) {
    __shared__ int   s_off[8][32][4];
    __shared__ float s_c[8][32][4];

    const int t  = threadIdx.x;
    const int r0 = blockIdx.x * 8;
    const int bq = r0 >> 14;

    {
        const int g = t >> 5, cmb = t & 31, h = cmb >> 2, p = cmb & 3;
        const int r = r0 + g;
        const int n = r & (NQ_ - 1);
        const int gi = n >> 7, gj = n & 127;
        const float* pr = pm + (size_t)r * 128;

        const float l0 = pr[64 + h * 4 + 0], l1 = pr[64 + h * 4 + 1];
        const float l2 = pr[64 + h * 4 + 2], l3 = pr[64 + h * 4 + 3];
        const float mx = fmaxf(fmaxf(l0, l1), fmaxf(l2, l3));
        const float sum = expf(l0 - mx) + expf(l1 - mx) + expf(l2 - mx) + expf(l3 - mx);
        const float lp = pr[64 + h * 4 + p];
        const float aw = expf(lp - mx) / sum;

        const float ox = pr[h * 8 + p * 2 + 0];
        const float oy = pr[h * 8 + p * 2 + 1];
        const float px = (gj * (1.0f / 127.0f) + ox * (1.0f / 128.0f)) * 128.0f - 0.5f;
        const float py = (gi * (1.0f / 127.0f) + oy * (1.0f / 128.0f)) * 128.0f - 0.5f;
        const float x0f = floorf(px), y0f = floorf(py);
        const int   x0 = (int)x0f, y0 = (int)y0f;
        const float fx = px - x0f, fy = py - y0f;
        const int x0c = min(max(x0, 0), 127), x1c = min(max(x0 + 1, 0), 127);
        const int y0c = min(max(y0, 0), 127), y1c = min(max(y0 + 1, 0), 127);
        const float vx0 = ((unsigned)x0 <= 127u) ? 1.f : 0.f;
        const float vx1 = ((unsigned)(x0 + 1) <= 127u) ? 1.f : 0.f;
        const float vy0 = ((unsigned)y0 <= 127u) ? 1.f : 0.f;
        const float vy1 = ((unsigned)(y0 + 1) <= 127u) ? 1.f : 0.f;

        s_off[g][cmb][0] = (y0c * 128 + x0c) * 512;
        s_off[g][cmb][1] = (y0c * 128 + x1c) * 512;
        s_off[g][cmb][2] = (y1c * 128 + x0c) * 512;
        s_off[g][cmb][3] = (y1c * 128 + x1c) * 512;
        s_c[g][cmb][0] = aw * (1.f - fx) * (1.f - fy) * vx0 * vy0;
        s_c[g][cmb][1] = aw * fx * (1.f - fy) * vx1 * vy0;
        s_c[g][cmb][2] = aw * (1.f - fx) * fy * vx0 * vy1;
        s_c[g][cmb][3] = aw * fx * fy * vx1 * vy1;
    }
    __syncthreads();

    const int half = t >> 7;
    const int h    = (t >> 4) & 7;
    const int dd   = t & 15;
    const char* vb = (const char*)vcomp + ((size_t)bq * NQ_ * 256 + h * 32 + dd * 2) * 2;

    #pragma unroll
    for (int it = 0; it < 4; ++it) {
        const int g = it * 2 + half;
        float a0 = 0.f, a1 = 0.f;
        #pragma unroll
        for (int p = 0; p < 4; ++p) {
            const int cmb = h * 4 + p;
            #pragma unroll
            for (int k = 0; k < 4; ++k) {
                const unsigned u = *(const unsigned*)(vb + s_off[g][cmb][k]);
                const float c = s_c[g][cmb][k];
                a0 += c * __uint_as_float(u << 16);
                a1 += c * __uint_as_float(u & 0xffff0000u);
            }
        }
        const int r = r0 + g;
        const unsigned o = (unsigned)(unsigned short)f2bf(a0)
                         | ((unsigned)(unsigned short)f2bf(a1) << 16);
        *(unsigned*)&msda[(size_t)r * 256 + h * 32 + dd * 2] = o;
    }
}

// ---------------------------------------------------------------------------
extern "C" void kernel_launch(void* const* d_in, const int* in_sizes, int n_in,
                              void* d_out, int out_size, void* d_ws, size_t ws_size,
                              hipStream_t stream) {
    const float* q      = (const float*)d_in[0];
    const float* b_out  = (const float*)d_in[8];
    const float* b1     = (const float*)d_in[10];
    const float* b2     = (const float*)d_in[12];
    const float* gamma  = (const float*)d_in[13];
    const float* beta   = (const float*)d_in[14];

    float* out = (float*)d_out;

    char* w = (char*)d_ws;
    float* pm    = (float*)w; w += (size_t)RTOT_ * 128 * 4;      // 16.8 MB
    short* vcomp = (short*)w; w += (size_t)RTOT_ * 256 * 2;      // 16.8 MB
    short* qbf   = (short*)w; w += (size_t)RTOT_ * EMBED_ * 2;   // 16.8 MB
    short* msda  = (short*)w; w += (size_t)RTOT_ * EMBED_ * 2;   // 16.8 MB
    short* xbf   = (short*)w; w += (size_t)RTOT_ * EMBED_ * 2;   // 16.8 MB
    short* WcatT = (short*)w; w += WCAT_ELEMS * 2;
    short* WoutT = (short*)w; w += WOUT_ELEMS * 2;
    short* W1T   = (short*)w; w += W1_ELEMS * 2;
    short* W2T   = (short*)w; w += W2_ELEMS * 2;
    float* bcat  = (float*)w; w += NCATP_ * 4;

    // q->bf16 + weight prep (one launch)
    prep_all<<<CVT_BLOCKS + PREP_BLOCKS, 256, 0, stream>>>(
        q, qbf,
        (const float*)d_in[5], (const float*)d_in[1], (const float*)d_in[3],
        (const float*)d_in[6], (const float*)d_in[2], (const float*)d_in[4],
        (const float*)d_in[7], (const float*)d_in[9], (const float*)d_in[11],
        WcatT, WoutT, W1T, W2T, bcat);

    // proj: vcomp (bf16 value) + pm (f32 meta)   (32768 x 384 x 256)
    gemm_mfma<EP_SPLIT><<<dim3(NCATP_ / 128, RTOT_ / 128), 256, 0, stream>>>(
        qbf, WcatT, bcat, nullptr, pm, vcomp, RTOT_, NCATP_, EMBED_);

    // MSDA sampling -> msda (bf16)
    msda_sample<<<RTOT_ / 8, 256, 0, stream>>>(pm, vcomp, msda);

    // xbf = bf16(msda @ W_out + b_out + 2q)   (32768 x 256 x 256)
    gemm_mfma<EP_ADD2Q_BF16><<<dim3(EMBED_ / 128, RTOT_ / 128), 256, 0, stream>>>(
        msda, WoutT, b_out, qbf, nullptr, xbf, RTOT_, EMBED_, EMBED_);

    // out = x + LN(relu(x@W1+b1)@W2 + b2)*gamma + beta   (fused FFN)
    ffn_ln<<<RTOT_ / 128, 512, 0, stream>>>(
        xbf, W1T, b1, W2T, b2, gamma, beta, out);
}